// Round 5
// baseline (455.613 us; speedup 1.0000x reference)
//
#include <hip/hip_runtime.h>
#include <stdint.h>

#define B_  8
#define C_  512
#define H_  96
#define W_  96
#define CQ_ 64
#define P_  (H_*W_)     // 9216 pixels per batch
#define NP  (B_*P_)     // 73728
#define L_  (W_+H_)     // 192 attn weights per pixel

typedef __attribute__((ext_vector_type(8))) short short8;
typedef __attribute__((ext_vector_type(4))) float f32x4;
typedef __attribute__((ext_vector_type(4))) unsigned short us4;

__device__ __forceinline__ ushort f2bf(float f) {
    uint32_t u = __builtin_bit_cast(uint32_t, f);
    u += 0x7fff + ((u >> 16) & 1);
    return (ushort)(u >> 16);
}
__device__ __forceinline__ float bf2f(ushort h) {
    uint32_t u = ((uint32_t)h) << 16;
    return __builtin_bit_cast(float, u);
}

// global -> LDS direct 16B copy (dest = wave-uniform base + lane*16)
#define GLL16(g, l) __builtin_amdgcn_global_load_lds( \
    (const __attribute__((address_space(1))) uint32_t*)(g), \
    (__attribute__((address_space(3))) uint32_t*)(l), 16, 0, 0)

// ---------------- K0a: x (b,c,p) fp32 -> x_t (b,p,c) bf16 ----------------
__global__ __launch_bounds__(256) void k_xt(const float* __restrict__ x, ushort* __restrict__ xt) {
    __shared__ float tile[64][65];
    int p0 = blockIdx.x * 64, c0 = blockIdx.y * 64, bat = blockIdx.z;
    int tx = threadIdx.x, ty = threadIdx.y;            // (32,8)
    const float* xb = x + ((size_t)bat * C_ + c0) * P_ + p0;
    #pragma unroll
    for (int i = ty; i < 64; i += 8) {
        float2 v = *(const float2*)&xb[(size_t)i * P_ + 2 * tx];
        tile[i][2 * tx] = v.x; tile[i][2 * tx + 1] = v.y;
    }
    __syncthreads();
    ushort* o = xt + ((size_t)bat * P_ + p0) * C_ + c0;
    #pragma unroll
    for (int i = ty; i < 64; i += 8) {
        ushort2 v; v.x = f2bf(tile[2 * tx][i]); v.y = f2bf(tile[2 * tx + 1][i]);
        *(ushort2*)&o[(size_t)i * C_ + 2 * tx] = v;
    }
}

// ---------------- K0b: weights -> bf16 combined [640][512]; ball[640] ----------------
__global__ __launch_bounds__(256) void k_wconv(const float* __restrict__ Wq, const float* __restrict__ Wk,
                                               const float* __restrict__ Wv, const float* __restrict__ bq,
                                               const float* __restrict__ bk, const float* __restrict__ bv,
                                               ushort* __restrict__ Wall, float* __restrict__ ball) {
    int idx = blockIdx.x * 256 + threadIdx.x;
    if (idx < 640) {
        float b;
        if (idx < 64)       b = bq[idx];
        else if (idx < 128) b = bk[idx - 64];
        else                b = bv[idx - 128];
        ball[idx] = b;
    }
    if (idx >= 640 * C_) return;
    int o = idx / C_, c = idx % C_;
    float v;
    if (o < 64)       v = Wq[o * C_ + c];
    else if (o < 128) v = Wk[(o - 64) * C_ + c];
    else              v = Wv[(o - 128) * C_ + c];
    Wall[idx] = f2bf(v);
}

// ---------------- K1: projection GEMM. M=640(all o) x N=64(pix), K=512. xt read ONCE. ----------------
// 8 waves, each 80(o) x 64(p). Linear LDS + chunk-XOR swizzle (source-side + read-side).
__global__ __launch_bounds__(512) void k_proj(const ushort* __restrict__ xt, const ushort* __restrict__ Wall,
                                              const float* __restrict__ ball,
                                              ushort* __restrict__ Qcm, ushort* __restrict__ Kcm,
                                              ushort* __restrict__ Vcm) {
    __shared__ __align__(16) ushort Al[640 * 32];     // [o][k] 40KB linear
    __shared__ __align__(16) ushort Bl[64 * 32];      // [pix][k] 4KB linear
    int tid = threadIdx.x, lane = tid & 63, wv = tid >> 6;
    // XCD swizzle: 1152 = 8 x 144
    int blk = ((int)blockIdx.x & 7) * 144 + ((int)blockIdx.x >> 3);
    int n0 = blk * 64;
    int bat = n0 / P_, pb0 = n0 - bat * P_;
    f32x4 acc[5][4] = {};
    for (int kb = 0; kb < C_; kb += 32) {
        #pragma unroll
        for (int i = 0; i < 5; ++i) {                 // A: 640 rows x 64B
            int u = tid + i * 512, row = u >> 2, seg = u & 3;
            GLL16(&Wall[(size_t)row * C_ + kb + ((seg ^ (row & 3)) << 3)], &Al[(size_t)u * 8]);
        }
        if (tid < 256) {                              // B: 64 rows x 64B
            int row = tid >> 2, seg = tid & 3;
            GLL16(&xt[(size_t)(n0 + row) * C_ + kb + ((seg ^ (row & 3)) << 3)], &Bl[(size_t)tid * 8]);
        }
        __syncthreads();
        int rr = lane & 15, gq = lane >> 4, ck = gq ^ (rr & 3);
        short8 fb[4];
        #pragma unroll
        for (int nt = 0; nt < 4; ++nt) fb[nt] = *(const short8*)&Bl[(nt * 16 + rr) * 32 + ck * 8];
        #pragma unroll
        for (int mt = 0; mt < 5; ++mt) {
            short8 fa = *(const short8*)&Al[(wv * 80 + mt * 16 + rr) * 32 + ck * 8];
            #pragma unroll
            for (int nt = 0; nt < 4; ++nt)
                acc[mt][nt] = __builtin_amdgcn_mfma_f32_16x16x32_bf16(fa, fb[nt], acc[mt][nt], 0, 0, 0);
        }
        __syncthreads();
    }
    int rr = lane & 15, gq = lane >> 4;
    #pragma unroll
    for (int mt = 0; mt < 5; ++mt)
        #pragma unroll
        for (int nt = 0; nt < 4; ++nt) {
            int col = nt * 16 + rr;
            #pragma unroll
            for (int q = 0; q < 4; ++q) {
                int o = wv * 80 + mt * 16 + gq * 4 + q;
                float v = acc[mt][nt][q] + ball[o];
                if (o < 64)       Qcm[(size_t)o * NP + n0 + col] = f2bf(v);
                else if (o < 128) Kcm[(size_t)(o - 64) * NP + n0 + col] = f2bf(v);
                else              Vcm[((size_t)bat * C_ + (o - 128)) * P_ + pb0 + col] = f2bf(v);
            }
        }
}

// ---------------- K1b: Qcm/Kcm [64][NP] -> Qb/Kb [NP][64] ----------------
__global__ __launch_bounds__(256) void k_qkt(const ushort* __restrict__ Qcm, const ushort* __restrict__ Kcm,
                                             ushort* __restrict__ Qb, ushort* __restrict__ Kb) {
    __shared__ ushort t[64][65];
    int p0 = blockIdx.x * 64;
    const ushort* src = blockIdx.y ? Kcm : Qcm;
    ushort* dst = blockIdx.y ? Kb : Qb;
    int tx = threadIdx.x, ty = threadIdx.y;            // (64,4)
    #pragma unroll
    for (int i = ty; i < 64; i += 4) t[i][tx] = src[(size_t)i * NP + p0 + tx];
    __syncthreads();
    #pragma unroll
    for (int i = ty; i < 64; i += 4) dst[(size_t)(p0 + i) * CQ_ + tx] = t[tx][i];
}

// ---------------- K3: Vcm (b,c,h,w) -> Vt (b,w,c,h); one plane per block ----------------
__global__ __launch_bounds__(256) void k_vt(const ushort* __restrict__ Vcm, ushort* __restrict__ Vt) {
    __shared__ ushort t[96 * 98];
    int c = blockIdx.x, bat = blockIdx.y;
    const ushort* src = Vcm + ((size_t)(bat * C_ + c)) * P_;
    int tid = threadIdx.x;
    for (int u = tid; u < 2304; u += 256) {
        int h = u / 24, w4 = (u % 24) * 4;
        us4 v = *(const us4*)&src[h * 96 + w4];
        ushort2 a; a.x = v.x; a.y = v.y;
        ushort2 b; b.x = v.z; b.y = v.w;
        *(ushort2*)&t[h * 98 + w4]     = a;
        *(ushort2*)&t[h * 98 + w4 + 2] = b;
    }
    __syncthreads();
    for (int u = tid; u < 2304; u += 256) {
        int w = u / 24, h4 = (u % 24) * 4;
        us4 o;
        o.x = t[(h4 + 0) * 98 + w];
        o.y = t[(h4 + 1) * 98 + w];
        o.z = t[(h4 + 2) * 98 + w];
        o.w = t[(h4 + 3) * 98 + w];
        *(us4*)&Vt[((size_t)(bat * W_ + w) * C_ + c) * H_ + h4] = o;
    }
}

// ---------------- K4: e_row. block (h,b): M=96(w) N=96(v) K=64; logits [pixel][96] fp32 ----------------
#define LSTR 40
__global__ __launch_bounds__(256) void k_erow(const ushort* __restrict__ Qb, const ushort* __restrict__ Kb,
                                              float* __restrict__ logits) {
    __shared__ __align__(16) ushort Al[96 * LSTR];
    __shared__ __align__(16) ushort Bl[96 * LSTR];
    int h = blockIdx.x, bat = blockIdx.y;
    int tid = threadIdx.x, lane = tid & 63, wvid = tid >> 6;
    int wr = wvid >> 1, wc = wvid & 1;                 // wave tile 48x48
    size_t base = ((size_t)bat * H_ + h) * W_;
    f32x4 acc[3][3] = {};
    for (int kb = 0; kb < CQ_; kb += 32) {
        for (int s = tid; s < 96 * 4; s += 256) {
            int row = s >> 2, seg = s & 3;
            *(short8*)&Al[row * LSTR + seg * 8] = *(const short8*)&Qb[(base + row) * CQ_ + kb + seg * 8];
            *(short8*)&Bl[row * LSTR + seg * 8] = *(const short8*)&Kb[(base + row) * CQ_ + kb + seg * 8];
        }
        __syncthreads();
        int rr = lane & 15, gq = lane >> 4;
        #pragma unroll
        for (int mt = 0; mt < 3; ++mt) {
            short8 fa = *(const short8*)&Al[(wr * 48 + mt * 16 + rr) * LSTR + gq * 8];
            #pragma unroll
            for (int nt = 0; nt < 3; ++nt) {
                short8 fb = *(const short8*)&Bl[(wc * 48 + nt * 16 + rr) * LSTR + gq * 8];
                acc[mt][nt] = __builtin_amdgcn_mfma_f32_16x16x32_bf16(fa, fb, acc[mt][nt], 0, 0, 0);
            }
        }
        __syncthreads();
    }
    int rr = lane & 15, gq = lane >> 4;
    #pragma unroll
    for (int mt = 0; mt < 3; ++mt)
        #pragma unroll
        for (int nt = 0; nt < 3; ++nt)
            #pragma unroll
            for (int q = 0; q < 4; ++q) {
                int w = wr * 48 + mt * 16 + gq * 4 + q;
                int v = wc * 48 + nt * 16 + rr;
                logits[(base + w) * 96 + v] = acc[mt][nt][q];
            }
}

// ---------------- K5: e_col GEMM + fused softmax. block (w,b). ----------------
// GEMM: M=96(h) N=96(g) K=64 -> e_col kept in LDS fp32. Then per-pixel softmax over
// [e_row (global, 96) | e_col (LDS, 96)], write attn bf16 [pixel][192].
__global__ __launch_bounds__(256) void k_ecolsm(const ushort* __restrict__ Qb, const ushort* __restrict__ Kb,
                                                const float* __restrict__ logits, ushort* __restrict__ attn) {
    __shared__ __align__(16) ushort Al[96 * LSTR];
    __shared__ __align__(16) ushort Bl[96 * LSTR];
    __shared__ float ecl[96 * 100];                   // [h][g] padded
    int w = blockIdx.x, bat = blockIdx.y;
    int tid = threadIdx.x, lane = tid & 63, wvid = tid >> 6;
    int wr = wvid >> 1, wc = wvid & 1;
    f32x4 acc[3][3] = {};
    for (int kb = 0; kb < CQ_; kb += 32) {
        for (int s = tid; s < 96 * 4; s += 256) {
            int row = s >> 2, seg = s & 3;
            size_t px = ((size_t)bat * H_ + row) * W_ + w;
            *(short8*)&Al[row * LSTR + seg * 8] = *(const short8*)&Qb[px * CQ_ + kb + seg * 8];
            *(short8*)&Bl[row * LSTR + seg * 8] = *(const short8*)&Kb[px * CQ_ + kb + seg * 8];
        }
        __syncthreads();
        int rr = lane & 15, gq = lane >> 4;
        #pragma unroll
        for (int mt = 0; mt < 3; ++mt) {
            short8 fa = *(const short8*)&Al[(wr * 48 + mt * 16 + rr) * LSTR + gq * 8];
            #pragma unroll
            for (int nt = 0; nt < 3; ++nt) {
                short8 fb = *(const short8*)&Bl[(wc * 48 + nt * 16 + rr) * LSTR + gq * 8];
                acc[mt][nt] = __builtin_amdgcn_mfma_f32_16x16x32_bf16(fa, fb, acc[mt][nt], 0, 0, 0);
            }
        }
        __syncthreads();
    }
    {   // spill e_col to LDS [h][g]
        int rr = lane & 15, gq = lane >> 4;
        #pragma unroll
        for (int mt = 0; mt < 3; ++mt)
            #pragma unroll
            for (int nt = 0; nt < 3; ++nt)
                #pragma unroll
                for (int q = 0; q < 4; ++q) {
                    int hh = wr * 48 + mt * 16 + gq * 4 + q;
                    int gg = wc * 48 + nt * 16 + rr;
                    ecl[hh * 100 + gg] = acc[mt][nt][q];
                }
    }
    __syncthreads();
    // fused softmax: wave wvid handles rows h = wvid, wvid+4, ...
    for (int h = wvid; h < H_; h += 4) {
        size_t pix = ((size_t)bat * H_ + h) * W_ + w;
        const float* lp = logits + pix * 96;
        float a  = lp[lane];
        float b  = (lane < 32) ? lp[64 + lane] : -1e30f;
        float c0 = ecl[h * 100 + lane];
        float c1 = (lane < 32) ? ecl[h * 100 + 64 + lane] : -1e30f;
        float m = fmaxf(fmaxf(a, b), fmaxf(c0, c1));
        #pragma unroll
        for (int off = 32; off; off >>= 1) m = fmaxf(m, __shfl_xor(m, off));
        float ea = __expf(a - m), eb = (lane < 32) ? __expf(b - m) : 0.0f;
        float ec0 = __expf(c0 - m), ec1 = (lane < 32) ? __expf(c1 - m) : 0.0f;
        float s = ea + eb + ec0 + ec1;
        #pragma unroll
        for (int off = 32; off; off >>= 1) s += __shfl_xor(s, off);
        float inv = 1.0f / s;
        ushort* ap = attn + pix * L_;
        ap[lane] = f2bf(ea * inv);
        ap[96 + lane] = f2bf(ec0 * inv);
        if (lane < 32) {
            ap[64 + lane] = f2bf(eb * inv);
            ap[160 + lane] = f2bf(ec1 * inv);
        }
    }
}

// ---------------- K8: col PV. block (w,b): M=512(c) N=96(h) K=96(g); out (b,c,w,h) ----------------
__global__ __launch_bounds__(512) void k_pvcol(const ushort* __restrict__ Vt, const ushort* __restrict__ attn,
                                               ushort* __restrict__ out1t) {
    __shared__ __align__(16) ushort Al[512 * 32];     // [c][g] 32KB linear
    __shared__ __align__(16) ushort Bl[96 * 32];      // [h][g] 6KB linear
    int w = blockIdx.x, bat = blockIdx.y;
    int tid = threadIdx.x, lane = tid & 63, wvid = tid >> 6;
    int wrm = wvid >> 1, wcn = wvid & 1;              // 4m x 2n, wave tile 128x48
    size_t vbase = ((size_t)bat * W_ + w) * C_ * H_;
    size_t abase = ((size_t)bat * P_ + w) * L_ + W_;
    f32x4 acc[8][3] = {};
    for (int kb = 0; kb < 96; kb += 32) {
        #pragma unroll
        for (int i = 0; i < 4; ++i) {
            int u = tid + i * 512, row = u >> 2, seg = u & 3;
            GLL16(&Vt[vbase + (size_t)row * H_ + kb + ((seg ^ (row & 3)) << 3)], &Al[(size_t)u * 8]);
        }
        if (tid < 384) {
            int row = tid >> 2, seg = tid & 3;
            GLL16(&attn[abase + (size_t)row * (W_ * L_) + kb + ((seg ^ (row & 3)) << 3)], &Bl[(size_t)tid * 8]);
        }
        __syncthreads();
        int rr = lane & 15, gq = lane >> 4, ck = gq ^ (rr & 3);
        short8 fb[3];
        #pragma unroll
        for (int nt = 0; nt < 3; ++nt) fb[nt] = *(const short8*)&Bl[(wcn * 48 + nt * 16 + rr) * 32 + ck * 8];
        #pragma unroll
        for (int mt = 0; mt < 8; ++mt) {
            short8 fa = *(const short8*)&Al[(wrm * 128 + mt * 16 + rr) * 32 + ck * 8];
            #pragma unroll
            for (int nt = 0; nt < 3; ++nt)
                acc[mt][nt] = __builtin_amdgcn_mfma_f32_16x16x32_bf16(fa, fb[nt], acc[mt][nt], 0, 0, 0);
        }
        __syncthreads();
    }
    int rr = lane & 15, gq = lane >> 4;
    #pragma unroll
    for (int mt = 0; mt < 8; ++mt)
        #pragma unroll
        for (int nt = 0; nt < 3; ++nt) {
            int hh = wcn * 48 + nt * 16 + rr;
            #pragma unroll
            for (int q = 0; q < 4; ++q) {
                int c = wrm * 128 + mt * 16 + gq * 4 + q;
                out1t[((size_t)(bat * C_ + c) * W_ + w) * H_ + hh] = f2bf(acc[mt][nt][q]);
            }
        }
}

// ---------------- K7: row PV. block (h,b): M=512(c) N=96(w) K=96(v) ----------------
__global__ __launch_bounds__(512) void k_pvrow(const ushort* __restrict__ Vcm, const ushort* __restrict__ attn,
                                               ushort* __restrict__ out0) {
    __shared__ __align__(16) ushort Al[512 * 32];     // [c][v] 32KB
    __shared__ __align__(16) ushort Bl[96 * 32];      // [w][v] 6KB
    int h = blockIdx.x, bat = blockIdx.y;
    int tid = threadIdx.x, lane = tid & 63, wvid = tid >> 6;
    int wrm = wvid >> 1, wcn = wvid & 1;
    size_t vbase = (size_t)bat * C_ * P_ + (size_t)h * W_;
    size_t abase = ((size_t)bat * H_ + h) * W_ * L_;
    f32x4 acc[8][3] = {};
    for (int kb = 0; kb < 96; kb += 32) {
        #pragma unroll
        for (int i = 0; i < 4; ++i) {
            int u = tid + i * 512, row = u >> 2, seg = u & 3;
            GLL16(&Vcm[vbase + (size_t)row * P_ + kb + ((seg ^ (row & 3)) << 3)], &Al[(size_t)u * 8]);
        }
        if (tid < 384) {
            int row = tid >> 2, seg = tid & 3;
            GLL16(&attn[abase + (size_t)row * L_ + kb + ((seg ^ (row & 3)) << 3)], &Bl[(size_t)tid * 8]);
        }
        __syncthreads();
        int rr = lane & 15, gq = lane >> 4, ck = gq ^ (rr & 3);
        short8 fb[3];
        #pragma unroll
        for (int nt = 0; nt < 3; ++nt) fb[nt] = *(const short8*)&Bl[(wcn * 48 + nt * 16 + rr) * 32 + ck * 8];
        #pragma unroll
        for (int mt = 0; mt < 8; ++mt) {
            short8 fa = *(const short8*)&Al[(wrm * 128 + mt * 16 + rr) * 32 + ck * 8];
            #pragma unroll
            for (int nt = 0; nt < 3; ++nt)
                acc[mt][nt] = __builtin_amdgcn_mfma_f32_16x16x32_bf16(fa, fb[nt], acc[mt][nt], 0, 0, 0);
        }
        __syncthreads();
    }
    int rr = lane & 15, gq = lane >> 4;
    #pragma unroll
    for (int mt = 0; mt < 8; ++mt)
        #pragma unroll
        for (int nt = 0; nt < 3; ++nt) {
            int w = wcn * 48 + nt * 16 + rr;
            #pragma unroll
            for (int q = 0; q < 4; ++q) {
                int c = wrm * 128 + mt * 16 + gq * 4 + q;
                out0[((size_t)bat * C_ + c) * P_ + (size_t)h * W_ + w] = f2bf(acc[mt][nt][q]);
            }
        }
}

// ---------------- K9: per-(b,c) plane: out = x + gamma*(out0 + out1t^T) ----------------
__global__ __launch_bounds__(256) void k_final(const float* __restrict__ x, const ushort* __restrict__ out0,
                                               const ushort* __restrict__ out1t, const float* __restrict__ gamma,
                                               float* __restrict__ out) {
    __shared__ ushort t[96 * 98];
    int c = blockIdx.x, bat = blockIdx.y;
    const ushort* src = out1t + ((size_t)bat * C_ + c) * P_;   // plane [w][h]
    int tid = threadIdx.x;
    for (int i = tid; i < 4608; i += 256) {
        int w = i / 48, h = (i % 48) * 2;
        ushort2 v = *(const ushort2*)&src[w * 96 + h];
        *(ushort2*)&t[w * 98 + h] = v;
    }
    __syncthreads();
    float gm = gamma[0];
    size_t base = ((size_t)bat * C_ + c) * P_;
    for (int i = tid; i < 4608; i += 256) {
        int h = i / 48, w = (i % 48) * 2;
        size_t idx = base + h * W_ + w;
        float2 xv = *(const float2*)&x[idx];
        ushort2 o0 = *(const ushort2*)&out0[idx];
        float2 r;
        r.x = xv.x + gm * (bf2f(o0.x) + bf2f(t[w * 98 + h]));
        r.y = xv.y + gm * (bf2f(o0.y) + bf2f(t[(w + 1) * 98 + h]));
        *(float2*)&out[idx] = r;
    }
}

extern "C" void kernel_launch(void* const* d_in, const int* in_sizes, int n_in,
                              void* d_out, int out_size, void* d_ws, size_t ws_size,
                              hipStream_t stream) {
    const float* x     = (const float*)d_in[0];
    const float* Wq    = (const float*)d_in[1];
    const float* bq    = (const float*)d_in[2];
    const float* Wk    = (const float*)d_in[3];
    const float* bk    = (const float*)d_in[4];
    const float* Wv    = (const float*)d_in[5];
    const float* bv    = (const float*)d_in[6];
    const float* gamma = (const float*)d_in[7];
    float* out = (float*)d_out;
    char* ws = (char*)d_ws;

    const size_t SZ  = (size_t)NP * C_ * 2;           // 75,497,472 B
    const size_t QKS = (size_t)NP * CQ_ * 2;          // 9,437,184 B
    const size_t LGS = (size_t)NP * 96 * 4;           // 28,311,552 B (row logits fp32)
    // Region0: xt (dead after k_proj) -> out1t
    ushort* xt     = (ushort*)(ws);
    ushort* out1t  = (ushort*)(ws);
    // Region1: Vcm
    ushort* Vcm    = (ushort*)(ws + SZ);
    // Region2: Vt (dead after pvcol) -> out0
    ushort* Vt     = (ushort*)(ws + 2 * SZ);
    ushort* out0   = Vt;
    // Region3: Qcm | Kcm | logits | attn  (= SZ total)
    ushort* Qcm    = (ushort*)(ws + 3 * SZ);
    ushort* Kcm    = (ushort*)(ws + 3 * SZ + QKS);
    float*  logits = (float*) (ws + 3 * SZ + 2 * QKS);
    ushort* attn   = (ushort*)(ws + 3 * SZ + 2 * QKS + LGS);
    // Region4: Qb | Kb | Wall | ball
    ushort* Qb     = (ushort*)(ws + 4 * SZ);
    ushort* Kb     = (ushort*)(ws + 4 * SZ + QKS);
    ushort* Wall   = (ushort*)(ws + 4 * SZ + 2 * QKS);
    float*  ball   = (float*) (ws + 4 * SZ + 2 * QKS + 640 * C_ * 2);

    k_wconv  <<<dim3(1280),       dim3(256),   0, stream>>>(Wq, Wk, Wv, bq, bk, bv, Wall, ball);
    k_xt     <<<dim3(144, 8, 8),  dim3(32, 8), 0, stream>>>(x, xt);
    k_proj   <<<dim3(1152),       dim3(512),   0, stream>>>(xt, Wall, ball, Qcm, Kcm, Vcm);
    k_qkt    <<<dim3(1152, 2),    dim3(64, 4), 0, stream>>>(Qcm, Kcm, Qb, Kb);
    k_vt     <<<dim3(512, 8),     dim3(256),   0, stream>>>(Vcm, Vt);
    k_erow   <<<dim3(96, 8),      dim3(256),   0, stream>>>(Qb, Kb, logits);
    k_ecolsm <<<dim3(96, 8),      dim3(256),   0, stream>>>(Qb, Kb, logits, attn);
    k_pvcol  <<<dim3(96, 8),      dim3(512),   0, stream>>>(Vt, attn, out1t);
    k_pvrow  <<<dim3(96, 8),      dim3(512),   0, stream>>>(Vcm, attn, out0);
    k_final  <<<dim3(512, 8),     dim3(256),   0, stream>>>(x, out0, out1t, gamma, out);
}

// Round 6
// 393.978 us; speedup vs baseline: 1.1564x; 1.1564x over previous
//
#include <hip/hip_runtime.h>
#include <stdint.h>

#define B_  8
#define C_  512
#define H_  96
#define W_  96
#define CQ_ 64
#define P_  (H_*W_)     // 9216 pixels per batch
#define NP  (B_*P_)     // 73728
#define L_  (W_+H_)     // 192 logits per pixel

typedef __attribute__((ext_vector_type(8))) short short8;
typedef __attribute__((ext_vector_type(4))) float f32x4;
typedef __attribute__((ext_vector_type(4))) unsigned short us4;

__device__ __forceinline__ ushort f2bf(float f) {
    uint32_t u = __builtin_bit_cast(uint32_t, f);
    u += 0x7fff + ((u >> 16) & 1);
    return (ushort)(u >> 16);
}
__device__ __forceinline__ float bf2f(ushort h) {
    uint32_t u = ((uint32_t)h) << 16;
    return __builtin_bit_cast(float, u);
}

// global -> LDS direct 16B copy (dest = wave-uniform base + lane*16)
#define GLL16(g, l) __builtin_amdgcn_global_load_lds( \
    (const __attribute__((address_space(1))) uint32_t*)(g), \
    (__attribute__((address_space(3))) uint32_t*)(l), 16, 0, 0)

// chunk swizzle: LDS[row][seg] holds global chunk seg^FSW(row); reads use ck = gq^FSW(row).
// Gives 8 distinct 16B slots per 16-lane group (2-way = free) for stride-64B b128 reads.
#define FSW(r) (((r) >> 1) & 3)

// ---------------- K0a: x (b,c,p) fp32 -> x_t (b,p,c) bf16 ----------------
__global__ __launch_bounds__(256) void k_xt(const float* __restrict__ x, ushort* __restrict__ xt) {
    __shared__ float tile[64][65];
    int p0 = blockIdx.x * 64, c0 = blockIdx.y * 64, bat = blockIdx.z;
    int tx = threadIdx.x, ty = threadIdx.y;            // (32,8)
    const float* xb = x + ((size_t)bat * C_ + c0) * P_ + p0;
    #pragma unroll
    for (int i = ty; i < 64; i += 8) {
        float2 v = *(const float2*)&xb[(size_t)i * P_ + 2 * tx];
        tile[i][2 * tx] = v.x; tile[i][2 * tx + 1] = v.y;
    }
    __syncthreads();
    ushort* o = xt + ((size_t)bat * P_ + p0) * C_ + c0;
    #pragma unroll
    for (int i = ty; i < 64; i += 8) {
        ushort2 v; v.x = f2bf(tile[2 * tx][i]); v.y = f2bf(tile[2 * tx + 1][i]);
        *(ushort2*)&o[(size_t)i * C_ + 2 * tx] = v;
    }
}

// ---------------- K0b: weights -> bf16 combined [640][512]; ball[640] ----------------
__global__ __launch_bounds__(256) void k_wconv(const float* __restrict__ Wq, const float* __restrict__ Wk,
                                               const float* __restrict__ Wv, const float* __restrict__ bq,
                                               const float* __restrict__ bk, const float* __restrict__ bv,
                                               ushort* __restrict__ Wall, float* __restrict__ ball) {
    int idx = blockIdx.x * 256 + threadIdx.x;
    if (idx < 640) {
        float b;
        if (idx < 64)       b = bq[idx];
        else if (idx < 128) b = bk[idx - 64];
        else                b = bv[idx - 128];
        ball[idx] = b;
    }
    if (idx >= 640 * C_) return;
    int o = idx / C_, c = idx % C_;
    float v;
    if (o < 64)       v = Wq[o * C_ + c];
    else if (o < 128) v = Wk[(o - 64) * C_ + c];
    else              v = Wv[(o - 128) * C_ + c];
    Wall[idx] = f2bf(v);
}

// ---------------- K1: projection GEMM (m97 structure + fixed swizzle) ----------------
// M=640(o) x N=NP(pix), K=512. tile 128x128, BK=32, 4 waves (2x2 of 64x64).
__global__ __launch_bounds__(256, 4) void k_proj(const ushort* __restrict__ xt, const ushort* __restrict__ Wall,
                                                 const float* __restrict__ ball,
                                                 ushort* __restrict__ Qcm, ushort* __restrict__ Kcm,
                                                 ushort* __restrict__ Vcm) {
    __shared__ __align__(16) ushort Al[128 * 32];     // [o][k] 8KB linear
    __shared__ __align__(16) ushort Bl[128 * 32];     // [pix][k] 8KB linear
    int tid = threadIdx.x, lane = tid & 63, wv = tid >> 6;
    int wr = wv >> 1, wc = wv & 1;
    // bijective XCD swizzle: 2880 blocks = 8 XCDs x 360; m fastest within chunk
    int wg = ((int)blockIdx.x & 7) * 360 + ((int)blockIdx.x >> 3);
    int m0 = (wg % 5) * 128;
    int n0 = (wg / 5) * 128;
    f32x4 acc[4][4] = {};
    for (int kb = 0; kb < C_; kb += 32) {
        #pragma unroll
        for (int i = 0; i < 2; ++i) {
            int u = tid + i * 256, row = u >> 2, seg = u & 3;
            int sg = (seg ^ FSW(row)) << 3;
            GLL16(&Wall[(size_t)(m0 + row) * C_ + kb + sg], &Al[(size_t)u * 8]);
            GLL16(&xt[(size_t)(n0 + row) * C_ + kb + sg],   &Bl[(size_t)u * 8]);
        }
        __syncthreads();
        int rr = lane & 15, gq = lane >> 4, ck = gq ^ FSW(rr);
        short8 fb[4];
        #pragma unroll
        for (int nt = 0; nt < 4; ++nt) fb[nt] = *(const short8*)&Bl[(wc * 64 + nt * 16 + rr) * 32 + ck * 8];
        #pragma unroll
        for (int mt = 0; mt < 4; ++mt) {
            short8 fa = *(const short8*)&Al[(wr * 64 + mt * 16 + rr) * 32 + ck * 8];
            #pragma unroll
            for (int nt = 0; nt < 4; ++nt)
                acc[mt][nt] = __builtin_amdgcn_mfma_f32_16x16x32_bf16(fa, fb[nt], acc[mt][nt], 0, 0, 0);
        }
        __syncthreads();
    }
    int rr = lane & 15, gq = lane >> 4;
    int bat = n0 / P_, pb0 = n0 - bat * P_;
    #pragma unroll
    for (int mt = 0; mt < 4; ++mt)
        #pragma unroll
        for (int nt = 0; nt < 4; ++nt) {
            int col = wc * 64 + nt * 16 + rr;
            #pragma unroll
            for (int q = 0; q < 4; ++q) {
                int o = m0 + wr * 64 + mt * 16 + gq * 4 + q;
                float v = acc[mt][nt][q] + ball[o];
                if (o < 64)       Qcm[(size_t)o * NP + n0 + col] = f2bf(v);
                else if (o < 128) Kcm[(size_t)(o - 64) * NP + n0 + col] = f2bf(v);
                else              Vcm[((size_t)bat * C_ + (o - 128)) * P_ + pb0 + col] = f2bf(v);
            }
        }
}

// ---------------- K1b: Qcm/Kcm [64][NP] -> Qb/Kb [NP][64] ----------------
__global__ __launch_bounds__(256) void k_qkt(const ushort* __restrict__ Qcm, const ushort* __restrict__ Kcm,
                                             ushort* __restrict__ Qb, ushort* __restrict__ Kb) {
    __shared__ ushort t[64][65];
    int p0 = blockIdx.x * 64;
    const ushort* src = blockIdx.y ? Kcm : Qcm;
    ushort* dst = blockIdx.y ? Kb : Qb;
    int tx = threadIdx.x, ty = threadIdx.y;            // (64,4)
    #pragma unroll
    for (int i = ty; i < 64; i += 4) t[i][tx] = src[(size_t)i * NP + p0 + tx];
    __syncthreads();
    #pragma unroll
    for (int i = ty; i < 64; i += 4) dst[(size_t)(p0 + i) * CQ_ + tx] = t[tx][i];
}

// ---------------- K3: Vcm (b,c,h,w) -> Vt (b,w,c,h); one plane per block ----------------
__global__ __launch_bounds__(256) void k_vt(const ushort* __restrict__ Vcm, ushort* __restrict__ Vt) {
    __shared__ ushort t[96 * 98];
    int c = blockIdx.x, bat = blockIdx.y;
    const ushort* src = Vcm + ((size_t)(bat * C_ + c)) * P_;
    int tid = threadIdx.x;
    for (int u = tid; u < 2304; u += 256) {
        int h = u / 24, w4 = (u % 24) * 4;
        us4 v = *(const us4*)&src[h * 96 + w4];
        ushort2 a; a.x = v.x; a.y = v.y;
        ushort2 b; b.x = v.z; b.y = v.w;
        *(ushort2*)&t[h * 98 + w4]     = a;
        *(ushort2*)&t[h * 98 + w4 + 2] = b;
    }
    __syncthreads();
    for (int u = tid; u < 2304; u += 256) {
        int w = u / 24, h4 = (u % 24) * 4;
        us4 o;
        o.x = t[(h4 + 0) * 98 + w];
        o.y = t[(h4 + 1) * 98 + w];
        o.z = t[(h4 + 2) * 98 + w];
        o.w = t[(h4 + 3) * 98 + w];
        *(us4*)&Vt[((size_t)(bat * W_ + w) * C_ + c) * H_ + h4] = o;
    }
}

// ---------------- K4: e_row. block (h,b): M=96(w) N=96(v) K=64 ----------------
#define LSTR 40
__global__ __launch_bounds__(256) void k_erow(const ushort* __restrict__ Qb, const ushort* __restrict__ Kb,
                                              float* __restrict__ logits) {
    __shared__ __align__(16) ushort Al[96 * LSTR];
    __shared__ __align__(16) ushort Bl[96 * LSTR];
    int h = blockIdx.x, bat = blockIdx.y;
    int tid = threadIdx.x, lane = tid & 63, wvid = tid >> 6;
    int wr = wvid >> 1, wc = wvid & 1;                 // wave tile 48x48
    size_t base = ((size_t)bat * H_ + h) * W_;
    f32x4 acc[3][3] = {};
    for (int kb = 0; kb < CQ_; kb += 32) {
        for (int s = tid; s < 96 * 4; s += 256) {
            int row = s >> 2, seg = s & 3;
            *(short8*)&Al[row * LSTR + seg * 8] = *(const short8*)&Qb[(base + row) * CQ_ + kb + seg * 8];
            *(short8*)&Bl[row * LSTR + seg * 8] = *(const short8*)&Kb[(base + row) * CQ_ + kb + seg * 8];
        }
        __syncthreads();
        int rr = lane & 15, gq = lane >> 4;
        #pragma unroll
        for (int mt = 0; mt < 3; ++mt) {
            short8 fa = *(const short8*)&Al[(wr * 48 + mt * 16 + rr) * LSTR + gq * 8];
            #pragma unroll
            for (int nt = 0; nt < 3; ++nt) {
                short8 fb = *(const short8*)&Bl[(wc * 48 + nt * 16 + rr) * LSTR + gq * 8];
                acc[mt][nt] = __builtin_amdgcn_mfma_f32_16x16x32_bf16(fa, fb, acc[mt][nt], 0, 0, 0);
            }
        }
        __syncthreads();
    }
    int rr = lane & 15, gq = lane >> 4;
    #pragma unroll
    for (int mt = 0; mt < 3; ++mt)
        #pragma unroll
        for (int nt = 0; nt < 3; ++nt)
            #pragma unroll
            for (int q = 0; q < 4; ++q) {
                int w = wr * 48 + mt * 16 + gq * 4 + q;
                int v = wc * 48 + nt * 16 + rr;
                logits[(base + w) * L_ + v] = acc[mt][nt][q];
            }
}

// ---------------- K5: e_col. block (w,b): M=96(h) N=96(g) K=64 ----------------
__global__ __launch_bounds__(256) void k_ecol(const ushort* __restrict__ Qb, const ushort* __restrict__ Kb,
                                              float* __restrict__ logits) {
    __shared__ __align__(16) ushort Al[96 * LSTR];
    __shared__ __align__(16) ushort Bl[96 * LSTR];
    int w = blockIdx.x, bat = blockIdx.y;
    int tid = threadIdx.x, lane = tid & 63, wvid = tid >> 6;
    int wr = wvid >> 1, wc = wvid & 1;
    f32x4 acc[3][3] = {};
    for (int kb = 0; kb < CQ_; kb += 32) {
        for (int s = tid; s < 96 * 4; s += 256) {
            int row = s >> 2, seg = s & 3;
            size_t px = ((size_t)bat * H_ + row) * W_ + w;
            *(short8*)&Al[row * LSTR + seg * 8] = *(const short8*)&Qb[px * CQ_ + kb + seg * 8];
            *(short8*)&Bl[row * LSTR + seg * 8] = *(const short8*)&Kb[px * CQ_ + kb + seg * 8];
        }
        __syncthreads();
        int rr = lane & 15, gq = lane >> 4;
        #pragma unroll
        for (int mt = 0; mt < 3; ++mt) {
            short8 fa = *(const short8*)&Al[(wr * 48 + mt * 16 + rr) * LSTR + gq * 8];
            #pragma unroll
            for (int nt = 0; nt < 3; ++nt) {
                short8 fb = *(const short8*)&Bl[(wc * 48 + nt * 16 + rr) * LSTR + gq * 8];
                acc[mt][nt] = __builtin_amdgcn_mfma_f32_16x16x32_bf16(fa, fb, acc[mt][nt], 0, 0, 0);
            }
        }
        __syncthreads();
    }
    int rr = lane & 15, gq = lane >> 4;
    #pragma unroll
    for (int mt = 0; mt < 3; ++mt)
        #pragma unroll
        for (int nt = 0; nt < 3; ++nt)
            #pragma unroll
            for (int q = 0; q < 4; ++q) {
                int hh = wr * 48 + mt * 16 + gq * 4 + q;
                int gg = wc * 48 + nt * 16 + rr;
                logits[(((size_t)bat * H_ + hh) * W_ + w) * L_ + W_ + gg] = acc[mt][nt][q];
            }
}

// ---------------- K6: softmax over 192, one wave per pixel ----------------
__global__ __launch_bounds__(256) void k_softmax(const float* __restrict__ logits, ushort* __restrict__ attn) {
    int wvid = threadIdx.x >> 6, lane = threadIdx.x & 63;
    size_t px = (size_t)blockIdx.x * 4 + wvid;
    const float* lp = logits + px * L_;
    float v0 = lp[lane], v1 = lp[lane + 64], v2 = lp[lane + 128];
    float m = fmaxf(fmaxf(v0, v1), v2);
    #pragma unroll
    for (int off = 32; off; off >>= 1) m = fmaxf(m, __shfl_xor(m, off));
    float e0 = __expf(v0 - m), e1 = __expf(v1 - m), e2 = __expf(v2 - m);
    float s = e0 + e1 + e2;
    #pragma unroll
    for (int off = 32; off; off >>= 1) s += __shfl_xor(s, off);
    float inv = 1.0f / s;
    ushort* ap = attn + px * L_;
    ap[lane] = f2bf(e0 * inv); ap[lane + 64] = f2bf(e1 * inv); ap[lane + 128] = f2bf(e2 * inv);
}

// ---------------- K8: col PV. block (w,b): M=512(c) N=96(h) K=96(g); out (b,c,w,h) ----------------
__global__ __launch_bounds__(512) void k_pvcol(const ushort* __restrict__ Vt, const ushort* __restrict__ attn,
                                               ushort* __restrict__ out1t) {
    __shared__ __align__(16) ushort Al[512 * 32];     // [c][g] 32KB linear
    __shared__ __align__(16) ushort Bl[96 * 32];      // [h][g] 6KB linear
    int w = blockIdx.x, bat = blockIdx.y;
    int tid = threadIdx.x, lane = tid & 63, wvid = tid >> 6;
    int wrm = wvid >> 1, wcn = wvid & 1;              // 4m x 2n, wave tile 128x48
    size_t vbase = ((size_t)bat * W_ + w) * C_ * H_;
    size_t abase = ((size_t)bat * P_ + w) * L_ + W_;
    f32x4 acc[8][3] = {};
    for (int kb = 0; kb < 96; kb += 32) {
        #pragma unroll
        for (int i = 0; i < 4; ++i) {
            int u = tid + i * 512, row = u >> 2, seg = u & 3;
            int sg = (seg ^ FSW(row)) << 3;
            GLL16(&Vt[vbase + (size_t)row * H_ + kb + sg], &Al[(size_t)u * 8]);
        }
        if (tid < 384) {
            int row = tid >> 2, seg = tid & 3;
            int sg = (seg ^ FSW(row)) << 3;
            GLL16(&attn[abase + (size_t)row * (W_ * L_) + kb + sg], &Bl[(size_t)tid * 8]);
        }
        __syncthreads();
        int rr = lane & 15, gq = lane >> 4, ck = gq ^ FSW(rr);
        short8 fb[3];
        #pragma unroll
        for (int nt = 0; nt < 3; ++nt) fb[nt] = *(const short8*)&Bl[(wcn * 48 + nt * 16 + rr) * 32 + ck * 8];
        #pragma unroll
        for (int mt = 0; mt < 8; ++mt) {
            short8 fa = *(const short8*)&Al[(wrm * 128 + mt * 16 + rr) * 32 + ck * 8];
            #pragma unroll
            for (int nt = 0; nt < 3; ++nt)
                acc[mt][nt] = __builtin_amdgcn_mfma_f32_16x16x32_bf16(fa, fb[nt], acc[mt][nt], 0, 0, 0);
        }
        __syncthreads();
    }
    int rr = lane & 15, gq = lane >> 4;
    #pragma unroll
    for (int mt = 0; mt < 8; ++mt)
        #pragma unroll
        for (int nt = 0; nt < 3; ++nt) {
            int hh = wcn * 48 + nt * 16 + rr;
            #pragma unroll
            for (int q = 0; q < 4; ++q) {
                int c = wrm * 128 + mt * 16 + gq * 4 + q;
                out1t[((size_t)(bat * C_ + c) * W_ + w) * H_ + hh] = f2bf(acc[mt][nt][q]);
            }
        }
}

// ---------------- K7: row PV. block (h,b): M=512(c) N=96(w) K=96(v) ----------------
__global__ __launch_bounds__(512) void k_pvrow(const ushort* __restrict__ Vcm, const ushort* __restrict__ attn,
                                               ushort* __restrict__ out0) {
    __shared__ __align__(16) ushort Al[512 * 32];     // [c][v] 32KB
    __shared__ __align__(16) ushort Bl[96 * 32];      // [w][v] 6KB
    int h = blockIdx.x, bat = blockIdx.y;
    int tid = threadIdx.x, lane = tid & 63, wvid = tid >> 6;
    int wrm = wvid >> 1, wcn = wvid & 1;
    size_t vbase = (size_t)bat * C_ * P_ + (size_t)h * W_;
    size_t abase = ((size_t)bat * H_ + h) * W_ * L_;
    f32x4 acc[8][3] = {};
    for (int kb = 0; kb < 96; kb += 32) {
        #pragma unroll
        for (int i = 0; i < 4; ++i) {
            int u = tid + i * 512, row = u >> 2, seg = u & 3;
            int sg = (seg ^ FSW(row)) << 3;
            GLL16(&Vcm[vbase + (size_t)row * P_ + kb + sg], &Al[(size_t)u * 8]);
        }
        if (tid < 384) {
            int row = tid >> 2, seg = tid & 3;
            int sg = (seg ^ FSW(row)) << 3;
            GLL16(&attn[abase + (size_t)row * L_ + kb + sg], &Bl[(size_t)tid * 8]);
        }
        __syncthreads();
        int rr = lane & 15, gq = lane >> 4, ck = gq ^ FSW(rr);
        short8 fb[3];
        #pragma unroll
        for (int nt = 0; nt < 3; ++nt) fb[nt] = *(const short8*)&Bl[(wcn * 48 + nt * 16 + rr) * 32 + ck * 8];
        #pragma unroll
        for (int mt = 0; mt < 8; ++mt) {
            short8 fa = *(const short8*)&Al[(wrm * 128 + mt * 16 + rr) * 32 + ck * 8];
            #pragma unroll
            for (int nt = 0; nt < 3; ++nt)
                acc[mt][nt] = __builtin_amdgcn_mfma_f32_16x16x32_bf16(fa, fb[nt], acc[mt][nt], 0, 0, 0);
        }
        __syncthreads();
    }
    int rr = lane & 15, gq = lane >> 4;
    #pragma unroll
    for (int mt = 0; mt < 8; ++mt)
        #pragma unroll
        for (int nt = 0; nt < 3; ++nt) {
            int w = wcn * 48 + nt * 16 + rr;
            #pragma unroll
            for (int q = 0; q < 4; ++q) {
                int c = wrm * 128 + mt * 16 + gq * 4 + q;
                out0[((size_t)bat * C_ + c) * P_ + (size_t)h * W_ + w] = f2bf(acc[mt][nt][q]);
            }
        }
}

// ---------------- K9: per-(b,c) plane: out = x + gamma*(out0 + out1t^T) ----------------
__global__ __launch_bounds__(256) void k_final(const float* __restrict__ x, const ushort* __restrict__ out0,
                                               const ushort* __restrict__ out1t, const float* __restrict__ gamma,
                                               float* __restrict__ out) {
    __shared__ ushort t[96 * 98];
    int c = blockIdx.x, bat = blockIdx.y;
    const ushort* src = out1t + ((size_t)bat * C_ + c) * P_;   // plane [w][h]
    int tid = threadIdx.x;
    for (int i = tid; i < 4608; i += 256) {
        int w = i / 48, h = (i % 48) * 2;
        ushort2 v = *(const ushort2*)&src[w * 96 + h];
        *(ushort2*)&t[w * 98 + h] = v;
    }
    __syncthreads();
    float gm = gamma[0];
    size_t base = ((size_t)bat * C_ + c) * P_;
    for (int i = tid; i < 4608; i += 256) {
        int h = i / 48, w = (i % 48) * 2;
        size_t idx = base + h * W_ + w;
        float2 xv = *(const float2*)&x[idx];
        ushort2 o0 = *(const ushort2*)&out0[idx];
        float2 r;
        r.x = xv.x + gm * (bf2f(o0.x) + bf2f(t[w * 98 + h]));
        r.y = xv.y + gm * (bf2f(o0.y) + bf2f(t[(w + 1) * 98 + h]));
        *(float2*)&out[idx] = r;
    }
}

extern "C" void kernel_launch(void* const* d_in, const int* in_sizes, int n_in,
                              void* d_out, int out_size, void* d_ws, size_t ws_size,
                              hipStream_t stream) {
    const float* x     = (const float*)d_in[0];
    const float* Wq    = (const float*)d_in[1];
    const float* bq    = (const float*)d_in[2];
    const float* Wk    = (const float*)d_in[3];
    const float* bk    = (const float*)d_in[4];
    const float* Wv    = (const float*)d_in[5];
    const float* bv    = (const float*)d_in[6];
    const float* gamma = (const float*)d_in[7];
    float* out = (float*)d_out;
    char* ws = (char*)d_ws;

    const size_t SZ  = (size_t)NP * C_ * 2;           // 75,497,472 B
    const size_t QKS = (size_t)NP * CQ_ * 2;          // 9,437,184 B
    // R0 [SZ]: xt (wconv..proj) -> out1t (pvcol..final)
    ushort* xt     = (ushort*)(ws);
    ushort* out1t  = (ushort*)(ws);
    // R1 [SZ]: Vcm (proj..pvrow)
    ushort* Vcm    = (ushort*)(ws + SZ);
    // R2 [SZ]: Vt (vt..pvcol) -> out0 (pvrow..final)
    ushort* Vt     = (ushort*)(ws + 2 * SZ);
    ushort* out0   = Vt;
    // R3 [SZ]: Qcm | Kcm (proj..qkt) | logits [pixel][192] fp32 (erow..softmax)
    ushort* Qcm    = (ushort*)(ws + 3 * SZ);
    ushort* Kcm    = (ushort*)(ws + 3 * SZ + QKS);
    float*  logits = (float*) (ws + 3 * SZ + 2 * QKS);
    // R4: Qb | Kb (qkt..ecol) -> attn (softmax..pvrow); then Wall after
    ushort* Qb     = (ushort*)(ws + 4 * SZ);
    ushort* Kb     = (ushort*)(ws + 4 * SZ + QKS);
    ushort* attn   = (ushort*)(ws + 4 * SZ);
    size_t off_wall = 4 * SZ + (size_t)NP * L_ * 2;
    ushort* Wall   = (ushort*)(ws + off_wall);
    float*  ball   = (float*) (ws + off_wall + 640 * C_ * 2);

    k_wconv  <<<dim3(1280),       dim3(256),   0, stream>>>(Wq, Wk, Wv, bq, bk, bv, Wall, ball);
    k_xt     <<<dim3(144, 8, 8),  dim3(32, 8), 0, stream>>>(x, xt);
    k_proj   <<<dim3(2880),       dim3(256),   0, stream>>>(xt, Wall, ball, Qcm, Kcm, Vcm);
    k_qkt    <<<dim3(1152, 2),    dim3(64, 4), 0, stream>>>(Qcm, Kcm, Qb, Kb);
    k_vt     <<<dim3(512, 8),     dim3(256),   0, stream>>>(Vcm, Vt);
    k_erow   <<<dim3(96, 8),      dim3(256),   0, stream>>>(Qb, Kb, logits);
    k_ecol   <<<dim3(96, 8),      dim3(256),   0, stream>>>(Qb, Kb, logits);
    k_softmax<<<dim3(NP / 4),     dim3(256),   0, stream>>>(logits, attn);
    k_pvcol  <<<dim3(96, 8),      dim3(512),   0, stream>>>(Vt, attn, out1t);
    k_pvrow  <<<dim3(96, 8),      dim3(512),   0, stream>>>(Vcm, attn, out0);
    k_final  <<<dim3(512, 8),     dim3(256),   0, stream>>>(x, out0, out1t, gamma, out);
}

// Round 7
// 363.007 us; speedup vs baseline: 1.2551x; 1.0853x over previous
//
#include <hip/hip_runtime.h>
#include <stdint.h>

#define B_  8
#define C_  512
#define H_  96
#define W_  96
#define CQ_ 64
#define P_  (H_*W_)     // 9216 pixels per batch
#define NP  (B_*P_)     // 73728
#define L_  (W_+H_)     // 192 logits per pixel

typedef __attribute__((ext_vector_type(8))) short short8;
typedef __attribute__((ext_vector_type(4))) float f32x4;
typedef __attribute__((ext_vector_type(4))) unsigned short us4;

__device__ __forceinline__ ushort f2bf(float f) {
    uint32_t u = __builtin_bit_cast(uint32_t, f);
    u += 0x7fff + ((u >> 16) & 1);
    return (ushort)(u >> 16);
}
__device__ __forceinline__ float bf2f(ushort h) {
    uint32_t u = ((uint32_t)h) << 16;
    return __builtin_bit_cast(float, u);
}

// global -> LDS direct 16B copy (dest = wave-uniform base + lane*16)
#define GLL16(g, l) __builtin_amdgcn_global_load_lds( \
    (const __attribute__((address_space(1))) uint32_t*)(g), \
    (__attribute__((address_space(3))) uint32_t*)(l), 16, 0, 0)

// chunk swizzle: LDS[row][seg] holds global chunk seg^FSW(row); reads use ck = gq^FSW(rr).
// 8 distinct 16B slots per 16-lane group (2-way = free) for stride-64B b128 reads.
#define FSW(r) (((r) >> 1) & 3)

// ---------------- K0a: x (b,c,p) fp32 -> x_t (b,p,c) bf16 ----------------
__global__ __launch_bounds__(256) void k_xt(const float* __restrict__ x, ushort* __restrict__ xt) {
    __shared__ float tile[64][65];
    int p0 = blockIdx.x * 64, c0 = blockIdx.y * 64, bat = blockIdx.z;
    int tx = threadIdx.x, ty = threadIdx.y;            // (32,8)
    const float* xb = x + ((size_t)bat * C_ + c0) * P_ + p0;
    #pragma unroll
    for (int i = ty; i < 64; i += 8) {
        float2 v = *(const float2*)&xb[(size_t)i * P_ + 2 * tx];
        tile[i][2 * tx] = v.x; tile[i][2 * tx + 1] = v.y;
    }
    __syncthreads();
    ushort* o = xt + ((size_t)bat * P_ + p0) * C_ + c0;
    #pragma unroll
    for (int i = ty; i < 64; i += 8) {
        ushort2 v; v.x = f2bf(tile[2 * tx][i]); v.y = f2bf(tile[2 * tx + 1][i]);
        *(ushort2*)&o[(size_t)i * C_ + 2 * tx] = v;
    }
}

// ---------------- K0b: weights -> bf16 combined [640][512]; ball[640] ----------------
__global__ __launch_bounds__(256) void k_wconv(const float* __restrict__ Wq, const float* __restrict__ Wk,
                                               const float* __restrict__ Wv, const float* __restrict__ bq,
                                               const float* __restrict__ bk, const float* __restrict__ bv,
                                               ushort* __restrict__ Wall, float* __restrict__ ball) {
    int idx = blockIdx.x * 256 + threadIdx.x;
    if (idx < 640) {
        float b;
        if (idx < 64)       b = bq[idx];
        else if (idx < 128) b = bk[idx - 64];
        else                b = bv[idx - 128];
        ball[idx] = b;
    }
    if (idx >= 640 * C_) return;
    int o = idx / C_, c = idx % C_;
    float v;
    if (o < 64)       v = Wq[o * C_ + c];
    else if (o < 128) v = Wk[(o - 64) * C_ + c];
    else              v = Wv[(o - 128) * C_ + c];
    Wall[idx] = f2bf(v);
}

// ---------------- K1: projection GEMM. M=640(o) x N=NP(pix), K=512, tile 128x128. ----------------
// m0==0 blocks (o<128 = Q|K): epilogue LDS-transpose -> write Qb/Kb pixel-major (k_qkt eliminated).
// m0>0 blocks: V channels, written channel-major to Vcm.
__global__ __launch_bounds__(256, 4) void k_proj(const ushort* __restrict__ xt, const ushort* __restrict__ Wall,
                                                 const float* __restrict__ ball,
                                                 ushort* __restrict__ Qb, ushort* __restrict__ Kb,
                                                 ushort* __restrict__ Vcm) {
    __shared__ __align__(16) ushort Al[128 * 32];     // [o][k] 8KB linear
    __shared__ __align__(16) ushort Bl[128 * 32];     // [pix][k] 8KB linear
    __shared__ __align__(16) ushort Tl[128 * 68];     // 17KB transpose buffer (m0==0 epilogue)
    int tid = threadIdx.x, lane = tid & 63, wv = tid >> 6;
    int wr = wv >> 1, wc = wv & 1;
    // bijective XCD swizzle: 2880 blocks = 8 XCDs x 360; m fastest within chunk
    int wg = ((int)blockIdx.x & 7) * 360 + ((int)blockIdx.x >> 3);
    int m0 = (wg % 5) * 128;
    int n0 = (wg / 5) * 128;
    f32x4 acc[4][4] = {};
    for (int kb = 0; kb < C_; kb += 32) {
        #pragma unroll
        for (int i = 0; i < 2; ++i) {
            int u = tid + i * 256, row = u >> 2, seg = u & 3;
            int sg = (seg ^ FSW(row)) << 3;
            GLL16(&Wall[(size_t)(m0 + row) * C_ + kb + sg], &Al[(size_t)u * 8]);
            GLL16(&xt[(size_t)(n0 + row) * C_ + kb + sg],   &Bl[(size_t)u * 8]);
        }
        __syncthreads();
        int rr = lane & 15, gq = lane >> 4, ck = gq ^ FSW(rr);
        short8 fb[4];
        #pragma unroll
        for (int nt = 0; nt < 4; ++nt) fb[nt] = *(const short8*)&Bl[(wc * 64 + nt * 16 + rr) * 32 + ck * 8];
        #pragma unroll
        for (int mt = 0; mt < 4; ++mt) {
            short8 fa = *(const short8*)&Al[(wr * 64 + mt * 16 + rr) * 32 + ck * 8];
            #pragma unroll
            for (int nt = 0; nt < 4; ++nt)
                acc[mt][nt] = __builtin_amdgcn_mfma_f32_16x16x32_bf16(fa, fb[nt], acc[mt][nt], 0, 0, 0);
        }
        __syncthreads();
    }
    int rr = lane & 15, gq = lane >> 4;
    int bat = n0 / P_, pb0 = n0 - bat * P_;
    if (m0 == 0) {
        // Q (wr==0, o 0..63) then K (wr==1, o 64..127): transpose to [pixel][o] and write coalesced
        #pragma unroll
        for (int pass = 0; pass < 2; ++pass) {
            __syncthreads();
            if (wr == pass) {
                #pragma unroll
                for (int mt = 0; mt < 4; ++mt)
                    #pragma unroll
                    for (int nt = 0; nt < 4; ++nt) {
                        int col = wc * 64 + nt * 16 + rr;
                        #pragma unroll
                        for (int q = 0; q < 4; ++q) {
                            int ol = mt * 16 + gq * 4 + q;           // 0..63
                            Tl[col * 68 + ol] = f2bf(acc[mt][nt][q] + ball[pass * 64 + ol]);
                        }
                    }
            }
            __syncthreads();
            ushort* dst = pass ? Kb : Qb;
            int p = tid >> 1, off = (tid & 1) * 32;
            #pragma unroll
            for (int j = 0; j < 8; ++j)
                *(us4*)&dst[(size_t)(n0 + p) * CQ_ + off + j * 4] = *(const us4*)&Tl[p * 68 + off + j * 4];
        }
    } else {
        #pragma unroll
        for (int mt = 0; mt < 4; ++mt)
            #pragma unroll
            for (int nt = 0; nt < 4; ++nt) {
                int col = wc * 64 + nt * 16 + rr;
                #pragma unroll
                for (int q = 0; q < 4; ++q) {
                    int o = m0 + wr * 64 + mt * 16 + gq * 4 + q;     // 128..639
                    int c = o - 128;
                    Vcm[((size_t)bat * C_ + c) * P_ + pb0 + col] = f2bf(acc[mt][nt][q] + ball[o]);
                }
            }
    }
}

// ---------------- K3: Vcm (b,c,h,w) -> Vt (b,w,c,h); one plane per block ----------------
__global__ __launch_bounds__(256) void k_vt(const ushort* __restrict__ Vcm, ushort* __restrict__ Vt) {
    __shared__ ushort t[96 * 98];
    int c = blockIdx.x, bat = blockIdx.y;
    const ushort* src = Vcm + ((size_t)(bat * C_ + c)) * P_;
    int tid = threadIdx.x;
    for (int u = tid; u < 2304; u += 256) {
        int h = u / 24, w4 = (u % 24) * 4;
        us4 v = *(const us4*)&src[h * 96 + w4];
        ushort2 a; a.x = v.x; a.y = v.y;
        ushort2 b; b.x = v.z; b.y = v.w;
        *(ushort2*)&t[h * 98 + w4]     = a;
        *(ushort2*)&t[h * 98 + w4 + 2] = b;
    }
    __syncthreads();
    for (int u = tid; u < 2304; u += 256) {
        int w = u / 24, h4 = (u % 24) * 4;
        us4 o;
        o.x = t[(h4 + 0) * 98 + w];
        o.y = t[(h4 + 1) * 98 + w];
        o.z = t[(h4 + 2) * 98 + w];
        o.w = t[(h4 + 3) * 98 + w];
        *(us4*)&Vt[((size_t)(bat * W_ + w) * C_ + c) * H_ + h4] = o;
    }
}

// ---------------- K4: e_row. block (h,b): M=96(w) N=96(v) K=64; writes bf16 into attn[pix][0:96] ----------------
#define LSTR 40
__global__ __launch_bounds__(256) void k_erow(const ushort* __restrict__ Qb, const ushort* __restrict__ Kb,
                                              ushort* __restrict__ attn) {
    __shared__ __align__(16) ushort Al[96 * LSTR];
    __shared__ __align__(16) ushort Bl[96 * LSTR];
    int h = blockIdx.x, bat = blockIdx.y;
    int tid = threadIdx.x, lane = tid & 63, wvid = tid >> 6;
    int wr = wvid >> 1, wc = wvid & 1;                 // wave tile 48x48
    size_t base = ((size_t)bat * H_ + h) * W_;
    f32x4 acc[3][3] = {};
    for (int kb = 0; kb < CQ_; kb += 32) {
        for (int s = tid; s < 96 * 4; s += 256) {
            int row = s >> 2, seg = s & 3;
            *(short8*)&Al[row * LSTR + seg * 8] = *(const short8*)&Qb[(base + row) * CQ_ + kb + seg * 8];
            *(short8*)&Bl[row * LSTR + seg * 8] = *(const short8*)&Kb[(base + row) * CQ_ + kb + seg * 8];
        }
        __syncthreads();
        int rr = lane & 15, gq = lane >> 4;
        #pragma unroll
        for (int mt = 0; mt < 3; ++mt) {
            short8 fa = *(const short8*)&Al[(wr * 48 + mt * 16 + rr) * LSTR + gq * 8];
            #pragma unroll
            for (int nt = 0; nt < 3; ++nt) {
                short8 fb = *(const short8*)&Bl[(wc * 48 + nt * 16 + rr) * LSTR + gq * 8];
                acc[mt][nt] = __builtin_amdgcn_mfma_f32_16x16x32_bf16(fa, fb, acc[mt][nt], 0, 0, 0);
            }
        }
        __syncthreads();
    }
    int rr = lane & 15, gq = lane >> 4;
    #pragma unroll
    for (int mt = 0; mt < 3; ++mt)
        #pragma unroll
        for (int nt = 0; nt < 3; ++nt)
            #pragma unroll
            for (int q = 0; q < 4; ++q) {
                int w = wr * 48 + mt * 16 + gq * 4 + q;
                int v = wc * 48 + nt * 16 + rr;
                attn[(base + w) * L_ + v] = f2bf(acc[mt][nt][q]);
            }
}

// ---------------- K5: e_col GEMM + fused softmax (in-place on attn). block (w,b). ----------------
// GEMM M=96(h) N=96(g) K=64 -> e_col bf16 in LDS. Softmax over [e_row(attn) | e_col(LDS)].
__global__ __launch_bounds__(256) void k_ecolsm(const ushort* __restrict__ Qb, const ushort* __restrict__ Kb,
                                                ushort* __restrict__ attn) {
    __shared__ __align__(16) ushort Al[96 * LSTR];
    __shared__ __align__(16) ushort Bl[96 * LSTR];
    __shared__ ushort ecl[96 * 100];                   // [h][g] bf16, padded
    int w = blockIdx.x, bat = blockIdx.y;
    int tid = threadIdx.x, lane = tid & 63, wvid = tid >> 6;
    int wr = wvid >> 1, wc = wvid & 1;
    f32x4 acc[3][3] = {};
    for (int kb = 0; kb < CQ_; kb += 32) {
        for (int s = tid; s < 96 * 4; s += 256) {
            int row = s >> 2, seg = s & 3;
            size_t px = ((size_t)bat * H_ + row) * W_ + w;
            *(short8*)&Al[row * LSTR + seg * 8] = *(const short8*)&Qb[px * CQ_ + kb + seg * 8];
            *(short8*)&Bl[row * LSTR + seg * 8] = *(const short8*)&Kb[px * CQ_ + kb + seg * 8];
        }
        __syncthreads();
        int rr = lane & 15, gq = lane >> 4;
        #pragma unroll
        for (int mt = 0; mt < 3; ++mt) {
            short8 fa = *(const short8*)&Al[(wr * 48 + mt * 16 + rr) * LSTR + gq * 8];
            #pragma unroll
            for (int nt = 0; nt < 3; ++nt) {
                short8 fb = *(const short8*)&Bl[(wc * 48 + nt * 16 + rr) * LSTR + gq * 8];
                acc[mt][nt] = __builtin_amdgcn_mfma_f32_16x16x32_bf16(fa, fb, acc[mt][nt], 0, 0, 0);
            }
        }
        __syncthreads();
    }
    {   // spill e_col to LDS bf16
        int rr = lane & 15, gq = lane >> 4;
        #pragma unroll
        for (int mt = 0; mt < 3; ++mt)
            #pragma unroll
            for (int nt = 0; nt < 3; ++nt)
                #pragma unroll
                for (int q = 0; q < 4; ++q) {
                    int hh = wr * 48 + mt * 16 + gq * 4 + q;
                    int gg = wc * 48 + nt * 16 + rr;
                    ecl[hh * 100 + gg] = f2bf(acc[mt][nt][q]);
                }
    }
    __syncthreads();
    // fused softmax: wave wvid handles rows h = wvid, wvid+4, ...
    for (int h = wvid; h < H_; h += 4) {
        size_t pix = ((size_t)bat * H_ + h) * W_ + w;
        ushort* ap = attn + pix * L_;
        float a  = bf2f(ap[lane]);
        float b  = (lane < 32) ? bf2f(ap[64 + lane]) : -1e30f;
        float c0 = bf2f(ecl[h * 100 + lane]);
        float c1 = (lane < 32) ? bf2f(ecl[h * 100 + 64 + lane]) : -1e30f;
        float m = fmaxf(fmaxf(a, b), fmaxf(c0, c1));
        #pragma unroll
        for (int off = 32; off; off >>= 1) m = fmaxf(m, __shfl_xor(m, off));
        float ea = __expf(a - m), eb = (lane < 32) ? __expf(b - m) : 0.0f;
        float ec0 = __expf(c0 - m), ec1 = (lane < 32) ? __expf(c1 - m) : 0.0f;
        float s = ea + eb + ec0 + ec1;
        #pragma unroll
        for (int off = 32; off; off >>= 1) s += __shfl_xor(s, off);
        float inv = 1.0f / s;
        ap[lane] = f2bf(ea * inv);
        ap[96 + lane] = f2bf(ec0 * inv);
        if (lane < 32) {
            ap[64 + lane] = f2bf(eb * inv);
            ap[160 + lane] = f2bf(ec1 * inv);
        }
    }
}

// ---------------- K8: col PV. block (w,b): M=512(c) N=96(h) K=96(g); out (b,c,w,h) ----------------
__global__ __launch_bounds__(512) void k_pvcol(const ushort* __restrict__ Vt, const ushort* __restrict__ attn,
                                               ushort* __restrict__ out1t) {
    __shared__ __align__(16) ushort Al[512 * 32];     // [c][g] 32KB linear
    __shared__ __align__(16) ushort Bl[96 * 32];      // [h][g] 6KB linear
    int w = blockIdx.x, bat = blockIdx.y;
    int tid = threadIdx.x, lane = tid & 63, wvid = tid >> 6;
    int wrm = wvid >> 1, wcn = wvid & 1;              // 4m x 2n, wave tile 128x48
    size_t vbase = ((size_t)bat * W_ + w) * C_ * H_;
    size_t abase = ((size_t)bat * P_ + w) * L_ + W_;
    f32x4 acc[8][3] = {};
    for (int kb = 0; kb < 96; kb += 32) {
        #pragma unroll
        for (int i = 0; i < 4; ++i) {
            int u = tid + i * 512, row = u >> 2, seg = u & 3;
            int sg = (seg ^ FSW(row)) << 3;
            GLL16(&Vt[vbase + (size_t)row * H_ + kb + sg], &Al[(size_t)u * 8]);
        }
        if (tid < 384) {
            int row = tid >> 2, seg = tid & 3;
            int sg = (seg ^ FSW(row)) << 3;
            GLL16(&attn[abase + (size_t)row * (W_ * L_) + kb + sg], &Bl[(size_t)tid * 8]);
        }
        __syncthreads();
        int rr = lane & 15, gq = lane >> 4, ck = gq ^ FSW(rr);
        short8 fb[3];
        #pragma unroll
        for (int nt = 0; nt < 3; ++nt) fb[nt] = *(const short8*)&Bl[(wcn * 48 + nt * 16 + rr) * 32 + ck * 8];
        #pragma unroll
        for (int mt = 0; mt < 8; ++mt) {
            short8 fa = *(const short8*)&Al[(wrm * 128 + mt * 16 + rr) * 32 + ck * 8];
            #pragma unroll
            for (int nt = 0; nt < 3; ++nt)
                acc[mt][nt] = __builtin_amdgcn_mfma_f32_16x16x32_bf16(fa, fb[nt], acc[mt][nt], 0, 0, 0);
        }
        __syncthreads();
    }
    int rr = lane & 15, gq = lane >> 4;
    #pragma unroll
    for (int mt = 0; mt < 8; ++mt)
        #pragma unroll
        for (int nt = 0; nt < 3; ++nt) {
            int hh = wcn * 48 + nt * 16 + rr;
            #pragma unroll
            for (int q = 0; q < 4; ++q) {
                int c = wrm * 128 + mt * 16 + gq * 4 + q;
                out1t[((size_t)(bat * C_ + c) * W_ + w) * H_ + hh] = f2bf(acc[mt][nt][q]);
            }
        }
}

// ---------------- K7: row PV. block (h,b): M=512(c) N=96(w) K=96(v) ----------------
__global__ __launch_bounds__(512) void k_pvrow(const ushort* __restrict__ Vcm, const ushort* __restrict__ attn,
                                               ushort* __restrict__ out0) {
    __shared__ __align__(16) ushort Al[512 * 32];     // [c][v] 32KB
    __shared__ __align__(16) ushort Bl[96 * 32];      // [w][v] 6KB
    int h = blockIdx.x, bat = blockIdx.y;
    int tid = threadIdx.x, lane = tid & 63, wvid = tid >> 6;
    int wrm = wvid >> 1, wcn = wvid & 1;
    size_t vbase = (size_t)bat * C_ * P_ + (size_t)h * W_;
    size_t abase = ((size_t)bat * H_ + h) * W_ * L_;
    f32x4 acc[8][3] = {};
    for (int kb = 0; kb < 96; kb += 32) {
        #pragma unroll
        for (int i = 0; i < 4; ++i) {
            int u = tid + i * 512, row = u >> 2, seg = u & 3;
            int sg = (seg ^ FSW(row)) << 3;
            GLL16(&Vcm[vbase + (size_t)row * P_ + kb + sg], &Al[(size_t)u * 8]);
        }
        if (tid < 384) {
            int row = tid >> 2, seg = tid & 3;
            int sg = (seg ^ FSW(row)) << 3;
            GLL16(&attn[abase + (size_t)row * L_ + kb + sg], &Bl[(size_t)tid * 8]);
        }
        __syncthreads();
        int rr = lane & 15, gq = lane >> 4, ck = gq ^ FSW(rr);
        short8 fb[3];
        #pragma unroll
        for (int nt = 0; nt < 3; ++nt) fb[nt] = *(const short8*)&Bl[(wcn * 48 + nt * 16 + rr) * 32 + ck * 8];
        #pragma unroll
        for (int mt = 0; mt < 8; ++mt) {
            short8 fa = *(const short8*)&Al[(wrm * 128 + mt * 16 + rr) * 32 + ck * 8];
            #pragma unroll
            for (int nt = 0; nt < 3; ++nt)
                acc[mt][nt] = __builtin_amdgcn_mfma_f32_16x16x32_bf16(fa, fb[nt], acc[mt][nt], 0, 0, 0);
        }
        __syncthreads();
    }
    int rr = lane & 15, gq = lane >> 4;
    #pragma unroll
    for (int mt = 0; mt < 8; ++mt)
        #pragma unroll
        for (int nt = 0; nt < 3; ++nt) {
            int w = wcn * 48 + nt * 16 + rr;
            #pragma unroll
            for (int q = 0; q < 4; ++q) {
                int c = wrm * 128 + mt * 16 + gq * 4 + q;
                out0[((size_t)bat * C_ + c) * P_ + (size_t)h * W_ + w] = f2bf(acc[mt][nt][q]);
            }
        }
}

// ---------------- K9: per-(b,c) plane: out = x + gamma*(out0 + out1t^T) ----------------
__global__ __launch_bounds__(256) void k_final(const float* __restrict__ x, const ushort* __restrict__ out0,
                                               const ushort* __restrict__ out1t, const float* __restrict__ gamma,
                                               float* __restrict__ out) {
    __shared__ ushort t[96 * 98];
    int c = blockIdx.x, bat = blockIdx.y;
    const ushort* src = out1t + ((size_t)bat * C_ + c) * P_;   // plane [w][h]
    int tid = threadIdx.x;
    for (int i = tid; i < 4608; i += 256) {
        int w = i / 48, h = (i % 48) * 2;
        ushort2 v = *(const ushort2*)&src[w * 96 + h];
        *(ushort2*)&t[w * 98 + h] = v;
    }
    __syncthreads();
    float gm = gamma[0];
    size_t base = ((size_t)bat * C_ + c) * P_;
    for (int i = tid; i < 4608; i += 256) {
        int h = i / 48, w = (i % 48) * 2;
        size_t idx = base + h * W_ + w;
        float2 xv = *(const float2*)&x[idx];
        ushort2 o0 = *(const ushort2*)&out0[idx];
        float2 r;
        r.x = xv.x + gm * (bf2f(o0.x) + bf2f(t[w * 98 + h]));
        r.y = xv.y + gm * (bf2f(o0.y) + bf2f(t[(w + 1) * 98 + h]));
        *(float2*)&out[idx] = r;
    }
}

extern "C" void kernel_launch(void* const* d_in, const int* in_sizes, int n_in,
                              void* d_out, int out_size, void* d_ws, size_t ws_size,
                              hipStream_t stream) {
    const float* x     = (const float*)d_in[0];
    const float* Wq    = (const float*)d_in[1];
    const float* bq    = (const float*)d_in[2];
    const float* Wk    = (const float*)d_in[3];
    const float* bk    = (const float*)d_in[4];
    const float* Wv    = (const float*)d_in[5];
    const float* bv    = (const float*)d_in[6];
    const float* gamma = (const float*)d_in[7];
    float* out = (float*)d_out;
    char* ws = (char*)d_ws;

    const size_t SZ  = (size_t)NP * C_ * 2;           // 75,497,472 B
    const size_t QKS = (size_t)NP * CQ_ * 2;          // 9,437,184 B
    // R0 [SZ]: xt (xt..proj) -> out1t (pvcol..final)
    ushort* xt     = (ushort*)(ws);
    ushort* out1t  = (ushort*)(ws);
    // R1 [SZ]: Vcm (proj..pvrow)
    ushort* Vcm    = (ushort*)(ws + SZ);
    // R2 [SZ]: Vt (vt..pvcol) -> out0 (pvrow..final)
    ushort* Vt     = (ushort*)(ws + 2 * SZ);
    ushort* out0   = Vt;
    // R3: Qb | Kb (proj..ecolsm) | attn (erow..pvrow) | Wall | ball
    ushort* Qb     = (ushort*)(ws + 3 * SZ);
    ushort* Kb     = (ushort*)(ws + 3 * SZ + QKS);
    ushort* attn   = (ushort*)(ws + 3 * SZ + 2 * QKS);
    size_t off_wall = 3 * SZ + 2 * QKS + (size_t)NP * L_ * 2;
    ushort* Wall   = (ushort*)(ws + off_wall);
    float*  ball   = (float*) (ws + off_wall + 640 * C_ * 2);

    k_wconv  <<<dim3(1280),       dim3(256),   0, stream>>>(Wq, Wk, Wv, bq, bk, bv, Wall, ball);
    k_xt     <<<dim3(144, 8, 8),  dim3(32, 8), 0, stream>>>(x, xt);
    k_proj   <<<dim3(2880),       dim3(256),   0, stream>>>(xt, Wall, ball, Qb, Kb, Vcm);
    k_vt     <<<dim3(512, 8),     dim3(256),   0, stream>>>(Vcm, Vt);
    k_erow   <<<dim3(96, 8),      dim3(256),   0, stream>>>(Qb, Kb, attn);
    k_ecolsm <<<dim3(96, 8),      dim3(256),   0, stream>>>(Qb, Kb, attn);
    k_pvcol  <<<dim3(96, 8),      dim3(512),   0, stream>>>(Vt, attn, out1t);
    k_pvrow  <<<dim3(96, 8),      dim3(512),   0, stream>>>(Vcm, attn, out0);
    k_final  <<<dim3(512, 8),     dim3(256),   0, stream>>>(x, out0, out1t, gamma, out);
}

// Round 8
// 356.182 us; speedup vs baseline: 1.2792x; 1.0192x over previous
//
#include <hip/hip_runtime.h>
#include <stdint.h>

#define B_  8
#define C_  512
#define H_  96
#define W_  96
#define CQ_ 64
#define P_  (H_*W_)     // 9216 pixels per batch
#define NP  (B_*P_)     // 73728
#define L_  (W_+H_)     // 192 logits per pixel

typedef __attribute__((ext_vector_type(8))) short short8;
typedef __attribute__((ext_vector_type(4))) float f32x4;
typedef __attribute__((ext_vector_type(4))) unsigned short us4;

__device__ __forceinline__ ushort f2bf(float f) {
    uint32_t u = __builtin_bit_cast(uint32_t, f);
    u += 0x7fff + ((u >> 16) & 1);
    return (ushort)(u >> 16);
}
__device__ __forceinline__ float bf2f(ushort h) {
    uint32_t u = ((uint32_t)h) << 16;
    return __builtin_bit_cast(float, u);
}

// global -> LDS direct 16B copy (dest = wave-uniform base + lane*16)
#define GLL16(g, l) __builtin_amdgcn_global_load_lds( \
    (const __attribute__((address_space(1))) uint32_t*)(g), \
    (__attribute__((address_space(3))) uint32_t*)(l), 16, 0, 0)

// chunk swizzle: LDS[row][seg] holds global chunk seg^FSW(row); reads use ck = gq^FSW(rr).
// 8 distinct 16B slots per 16-lane group (2-way = free) for stride-64B b128 reads.
#define FSW(r) (((r) >> 1) & 3)

// ---------------- K0a: x (b,c,p) fp32 -> x_t (b,p,c) bf16 (vectorized) ----------------
__global__ __launch_bounds__(256) void k_xt(const float* __restrict__ x, ushort* __restrict__ xt) {
    __shared__ float tile[64][65];
    int p0 = blockIdx.x * 64, c0 = blockIdx.y * 64, bat = blockIdx.z;
    int tid = threadIdx.x;
    const float* xb = x + ((size_t)bat * C_ + c0) * P_ + p0;
    #pragma unroll
    for (int k = 0; k < 4; ++k) {                      // 64 c-rows x 16 float4
        int u = tid + k * 256, row = u >> 4, p4 = (u & 15) * 4;
        float4 v = *(const float4*)&xb[(size_t)row * P_ + p4];
        tile[row][p4] = v.x; tile[row][p4 + 1] = v.y; tile[row][p4 + 2] = v.z; tile[row][p4 + 3] = v.w;
    }
    __syncthreads();
    ushort* o = xt + ((size_t)bat * P_ + p0) * C_ + c0;
    #pragma unroll
    for (int k = 0; k < 4; ++k) {                      // 64 p-rows x 16 us4 (c)
        int u = tid + k * 256, p = u >> 4, c4 = (u & 15) * 4;
        us4 v;
        v.x = f2bf(tile[c4 + 0][p]); v.y = f2bf(tile[c4 + 1][p]);
        v.z = f2bf(tile[c4 + 2][p]); v.w = f2bf(tile[c4 + 3][p]);
        *(us4*)&o[(size_t)p * C_ + c4] = v;
    }
}

// ---------------- K0b: weights -> bf16 combined [640][512]; ball[640] ----------------
__global__ __launch_bounds__(256) void k_wconv(const float* __restrict__ Wq, const float* __restrict__ Wk,
                                               const float* __restrict__ Wv, const float* __restrict__ bq,
                                               const float* __restrict__ bk, const float* __restrict__ bv,
                                               ushort* __restrict__ Wall, float* __restrict__ ball) {
    int idx = blockIdx.x * 256 + threadIdx.x;
    if (idx < 640) {
        float b;
        if (idx < 64)       b = bq[idx];
        else if (idx < 128) b = bk[idx - 64];
        else                b = bv[idx - 128];
        ball[idx] = b;
    }
    if (idx >= 640 * C_) return;
    int o = idx / C_, c = idx % C_;
    float v;
    if (o < 64)       v = Wq[o * C_ + c];
    else if (o < 128) v = Wk[(o - 64) * C_ + c];
    else              v = Wv[(o - 128) * C_ + c];
    Wall[idx] = f2bf(v);
}

// ---------------- K1: projection GEMM. M=640(o) x N=NP(pix), K=512, tile 128x128. ----------------
// m0==0 blocks (o<128 = Q|K): epilogue LDS-transpose -> write Qb/Kb pixel-major.
// m0>0 blocks: V channels, written channel-major to Vcm.
__global__ __launch_bounds__(256, 4) void k_proj(const ushort* __restrict__ xt, const ushort* __restrict__ Wall,
                                                 const float* __restrict__ ball,
                                                 ushort* __restrict__ Qb, ushort* __restrict__ Kb,
                                                 ushort* __restrict__ Vcm) {
    __shared__ __align__(16) ushort Al[128 * 32];     // [o][k] 8KB linear
    __shared__ __align__(16) ushort Bl[128 * 32];     // [pix][k] 8KB linear
    __shared__ __align__(16) ushort Tl[128 * 68];     // 17KB transpose buffer (m0==0 epilogue)
    int tid = threadIdx.x, lane = tid & 63, wv = tid >> 6;
    int wr = wv >> 1, wc = wv & 1;
    // bijective XCD swizzle: 2880 blocks = 8 XCDs x 360; m fastest within chunk
    int wg = ((int)blockIdx.x & 7) * 360 + ((int)blockIdx.x >> 3);
    int m0 = (wg % 5) * 128;
    int n0 = (wg / 5) * 128;
    f32x4 acc[4][4] = {};
    for (int kb = 0; kb < C_; kb += 32) {
        #pragma unroll
        for (int i = 0; i < 2; ++i) {
            int u = tid + i * 256, row = u >> 2, seg = u & 3;
            int sg = (seg ^ FSW(row)) << 3;
            GLL16(&Wall[(size_t)(m0 + row) * C_ + kb + sg], &Al[(size_t)u * 8]);
            GLL16(&xt[(size_t)(n0 + row) * C_ + kb + sg],   &Bl[(size_t)u * 8]);
        }
        __syncthreads();
        int rr = lane & 15, gq = lane >> 4, ck = gq ^ FSW(rr);
        short8 fb[4];
        #pragma unroll
        for (int nt = 0; nt < 4; ++nt) fb[nt] = *(const short8*)&Bl[(wc * 64 + nt * 16 + rr) * 32 + ck * 8];
        #pragma unroll
        for (int mt = 0; mt < 4; ++mt) {
            short8 fa = *(const short8*)&Al[(wr * 64 + mt * 16 + rr) * 32 + ck * 8];
            #pragma unroll
            for (int nt = 0; nt < 4; ++nt)
                acc[mt][nt] = __builtin_amdgcn_mfma_f32_16x16x32_bf16(fa, fb[nt], acc[mt][nt], 0, 0, 0);
        }
        __syncthreads();
    }
    int rr = lane & 15, gq = lane >> 4;
    int bat = n0 / P_, pb0 = n0 - bat * P_;
    if (m0 == 0) {
        // Q (wr==0, o 0..63) then K (wr==1, o 64..127): transpose to [pixel][o], coalesced write
        #pragma unroll
        for (int pass = 0; pass < 2; ++pass) {
            __syncthreads();
            if (wr == pass) {
                #pragma unroll
                for (int mt = 0; mt < 4; ++mt)
                    #pragma unroll
                    for (int nt = 0; nt < 4; ++nt) {
                        int col = wc * 64 + nt * 16 + rr;
                        #pragma unroll
                        for (int q = 0; q < 4; ++q) {
                            int ol = mt * 16 + gq * 4 + q;           // 0..63
                            Tl[col * 68 + ol] = f2bf(acc[mt][nt][q] + ball[pass * 64 + ol]);
                        }
                    }
            }
            __syncthreads();
            ushort* dst = pass ? Kb : Qb;
            int p = tid >> 1, off = (tid & 1) * 32;
            #pragma unroll
            for (int j = 0; j < 8; ++j)
                *(us4*)&dst[(size_t)(n0 + p) * CQ_ + off + j * 4] = *(const us4*)&Tl[p * 68 + off + j * 4];
        }
    } else {
        #pragma unroll
        for (int mt = 0; mt < 4; ++mt)
            #pragma unroll
            for (int nt = 0; nt < 4; ++nt) {
                int col = wc * 64 + nt * 16 + rr;
                #pragma unroll
                for (int q = 0; q < 4; ++q) {
                    int o = m0 + wr * 64 + mt * 16 + gq * 4 + q;     // 128..639
                    int c = o - 128;
                    Vcm[((size_t)bat * C_ + c) * P_ + pb0 + col] = f2bf(acc[mt][nt][q] + ball[o]);
                }
            }
    }
}

// ---------------- K3: Vcm (b,c,h,w) -> Vt (b,w,c,h); one plane per block ----------------
__global__ __launch_bounds__(256) void k_vt(const ushort* __restrict__ Vcm, ushort* __restrict__ Vt) {
    __shared__ ushort t[96 * 98];
    int c = blockIdx.x, bat = blockIdx.y;
    const ushort* src = Vcm + ((size_t)(bat * C_ + c)) * P_;
    int tid = threadIdx.x;
    for (int u = tid; u < 2304; u += 256) {
        int h = u / 24, w4 = (u % 24) * 4;
        us4 v = *(const us4*)&src[h * 96 + w4];
        ushort2 a; a.x = v.x; a.y = v.y;
        ushort2 b; b.x = v.z; b.y = v.w;
        *(ushort2*)&t[h * 98 + w4]     = a;
        *(ushort2*)&t[h * 98 + w4 + 2] = b;
    }
    __syncthreads();
    for (int u = tid; u < 2304; u += 256) {
        int w = u / 24, h4 = (u % 24) * 4;
        us4 o;
        o.x = t[(h4 + 0) * 98 + w];
        o.y = t[(h4 + 1) * 98 + w];
        o.z = t[(h4 + 2) * 98 + w];
        o.w = t[(h4 + 3) * 98 + w];
        *(us4*)&Vt[((size_t)(bat * W_ + w) * C_ + c) * H_ + h4] = o;
    }
}

// ---------------- K4: e_row. block (h,b): M=96(w) N=96(v) K=64; bf16 into attn[pix][0:96] ----------------
#define LSTR 40
__global__ __launch_bounds__(256) void k_erow(const ushort* __restrict__ Qb, const ushort* __restrict__ Kb,
                                              ushort* __restrict__ attn) {
    __shared__ __align__(16) ushort Al[96 * LSTR];
    __shared__ __align__(16) ushort Bl[96 * LSTR];
    int h = blockIdx.x, bat = blockIdx.y;
    int tid = threadIdx.x, lane = tid & 63, wvid = tid >> 6;
    int wr = wvid >> 1, wc = wvid & 1;                 // wave tile 48x48
    size_t base = ((size_t)bat * H_ + h) * W_;
    f32x4 acc[3][3] = {};
    for (int kb = 0; kb < CQ_; kb += 32) {
        for (int s = tid; s < 96 * 4; s += 256) {
            int row = s >> 2, seg = s & 3;
            *(short8*)&Al[row * LSTR + seg * 8] = *(const short8*)&Qb[(base + row) * CQ_ + kb + seg * 8];
            *(short8*)&Bl[row * LSTR + seg * 8] = *(const short8*)&Kb[(base + row) * CQ_ + kb + seg * 8];
        }
        __syncthreads();
        int rr = lane & 15, gq = lane >> 4;
        #pragma unroll
        for (int mt = 0; mt < 3; ++mt) {
            short8 fa = *(const short8*)&Al[(wr * 48 + mt * 16 + rr) * LSTR + gq * 8];
            #pragma unroll
            for (int nt = 0; nt < 3; ++nt) {
                short8 fb = *(const short8*)&Bl[(wc * 48 + nt * 16 + rr) * LSTR + gq * 8];
                acc[mt][nt] = __builtin_amdgcn_mfma_f32_16x16x32_bf16(fa, fb, acc[mt][nt], 0, 0, 0);
            }
        }
        __syncthreads();
    }
    int rr = lane & 15, gq = lane >> 4;
    #pragma unroll
    for (int mt = 0; mt < 3; ++mt)
        #pragma unroll
        for (int nt = 0; nt < 3; ++nt)
            #pragma unroll
            for (int q = 0; q < 4; ++q) {
                int w = wr * 48 + mt * 16 + gq * 4 + q;
                int v = wc * 48 + nt * 16 + rr;
                attn[(base + w) * L_ + v] = f2bf(acc[mt][nt][q]);
            }
}

// ---------------- K5: e_col GEMM + fused softmax (in-place on attn). block (w,b). ----------------
__global__ __launch_bounds__(256) void k_ecolsm(const ushort* __restrict__ Qb, const ushort* __restrict__ Kb,
                                                ushort* __restrict__ attn) {
    __shared__ __align__(16) ushort Al[96 * LSTR];
    __shared__ __align__(16) ushort Bl[96 * LSTR];
    __shared__ ushort ecl[96 * 100];                   // [h][g] bf16, padded
    int w = blockIdx.x, bat = blockIdx.y;
    int tid = threadIdx.x, lane = tid & 63, wvid = tid >> 6;
    int wr = wvid >> 1, wc = wvid & 1;
    f32x4 acc[3][3] = {};
    for (int kb = 0; kb < CQ_; kb += 32) {
        for (int s = tid; s < 96 * 4; s += 256) {
            int row = s >> 2, seg = s & 3;
            size_t px = ((size_t)bat * H_ + row) * W_ + w;
            *(short8*)&Al[row * LSTR + seg * 8] = *(const short8*)&Qb[px * CQ_ + kb + seg * 8];
            *(short8*)&Bl[row * LSTR + seg * 8] = *(const short8*)&Kb[px * CQ_ + kb + seg * 8];
        }
        __syncthreads();
        int rr = lane & 15, gq = lane >> 4;
        #pragma unroll
        for (int mt = 0; mt < 3; ++mt) {
            short8 fa = *(const short8*)&Al[(wr * 48 + mt * 16 + rr) * LSTR + gq * 8];
            #pragma unroll
            for (int nt = 0; nt < 3; ++nt) {
                short8 fb = *(const short8*)&Bl[(wc * 48 + nt * 16 + rr) * LSTR + gq * 8];
                acc[mt][nt] = __builtin_amdgcn_mfma_f32_16x16x32_bf16(fa, fb, acc[mt][nt], 0, 0, 0);
            }
        }
        __syncthreads();
    }
    {   // spill e_col to LDS bf16
        int rr = lane & 15, gq = lane >> 4;
        #pragma unroll
        for (int mt = 0; mt < 3; ++mt)
            #pragma unroll
            for (int nt = 0; nt < 3; ++nt)
                #pragma unroll
                for (int q = 0; q < 4; ++q) {
                    int hh = wr * 48 + mt * 16 + gq * 4 + q;
                    int gg = wc * 48 + nt * 16 + rr;
                    ecl[hh * 100 + gg] = f2bf(acc[mt][nt][q]);
                }
    }
    __syncthreads();
    for (int h = wvid; h < H_; h += 4) {
        size_t pix = ((size_t)bat * H_ + h) * W_ + w;
        ushort* ap = attn + pix * L_;
        float a  = bf2f(ap[lane]);
        float b  = (lane < 32) ? bf2f(ap[64 + lane]) : -1e30f;
        float c0 = bf2f(ecl[h * 100 + lane]);
        float c1 = (lane < 32) ? bf2f(ecl[h * 100 + 64 + lane]) : -1e30f;
        float m = fmaxf(fmaxf(a, b), fmaxf(c0, c1));
        #pragma unroll
        for (int off = 32; off; off >>= 1) m = fmaxf(m, __shfl_xor(m, off));
        float ea = __expf(a - m), eb = (lane < 32) ? __expf(b - m) : 0.0f;
        float ec0 = __expf(c0 - m), ec1 = (lane < 32) ? __expf(c1 - m) : 0.0f;
        float s = ea + eb + ec0 + ec1;
        #pragma unroll
        for (int off = 32; off; off >>= 1) s += __shfl_xor(s, off);
        float inv = 1.0f / s;
        ap[lane] = f2bf(ea * inv);
        ap[96 + lane] = f2bf(ec0 * inv);
        if (lane < 32) {
            ap[64 + lane] = f2bf(eb * inv);
            ap[160 + lane] = f2bf(ec1 * inv);
        }
    }
}

// ---------------- K8: col PV. block (w,b): M=512(c) N=96(h) K=96(g); out (b,c,w,h) ----------------
__global__ __launch_bounds__(512) void k_pvcol(const ushort* __restrict__ Vt, const ushort* __restrict__ attn,
                                               ushort* __restrict__ out1t) {
    __shared__ __align__(16) ushort Al[512 * 32];     // [c][g] 32KB linear
    __shared__ __align__(16) ushort Bl[96 * 32];      // [h][g] 6KB linear
    int w = blockIdx.x, bat = blockIdx.y;
    int tid = threadIdx.x, lane = tid & 63, wvid = tid >> 6;
    int wrm = wvid >> 1, wcn = wvid & 1;              // 4m x 2n, wave tile 128x48
    size_t vbase = ((size_t)bat * W_ + w) * C_ * H_;
    size_t abase = ((size_t)bat * P_ + w) * L_ + W_;
    f32x4 acc[8][3] = {};
    for (int kb = 0; kb < 96; kb += 32) {
        #pragma unroll
        for (int i = 0; i < 4; ++i) {
            int u = tid + i * 512, row = u >> 2, seg = u & 3;
            int sg = (seg ^ FSW(row)) << 3;
            GLL16(&Vt[vbase + (size_t)row * H_ + kb + sg], &Al[(size_t)u * 8]);
        }
        if (tid < 384) {
            int row = tid >> 2, seg = tid & 3;
            int sg = (seg ^ FSW(row)) << 3;
            GLL16(&attn[abase + (size_t)row * (W_ * L_) + kb + sg], &Bl[(size_t)tid * 8]);
        }
        __syncthreads();
        int rr = lane & 15, gq = lane >> 4, ck = gq ^ FSW(rr);
        short8 fb[3];
        #pragma unroll
        for (int nt = 0; nt < 3; ++nt) fb[nt] = *(const short8*)&Bl[(wcn * 48 + nt * 16 + rr) * 32 + ck * 8];
        #pragma unroll
        for (int mt = 0; mt < 8; ++mt) {
            short8 fa = *(const short8*)&Al[(wrm * 128 + mt * 16 + rr) * 32 + ck * 8];
            #pragma unroll
            for (int nt = 0; nt < 3; ++nt)
                acc[mt][nt] = __builtin_amdgcn_mfma_f32_16x16x32_bf16(fa, fb[nt], acc[mt][nt], 0, 0, 0);
        }
        __syncthreads();
    }
    int rr = lane & 15, gq = lane >> 4;
    #pragma unroll
    for (int mt = 0; mt < 8; ++mt)
        #pragma unroll
        for (int nt = 0; nt < 3; ++nt) {
            int hh = wcn * 48 + nt * 16 + rr;
            #pragma unroll
            for (int q = 0; q < 4; ++q) {
                int c = wrm * 128 + mt * 16 + gq * 4 + q;
                out1t[((size_t)(bat * C_ + c) * W_ + w) * H_ + hh] = f2bf(acc[mt][nt][q]);
            }
        }
}

// ---------------- K7: row PV. block (h,b): M=512(c) N=96(w) K=96(v) ----------------
__global__ __launch_bounds__(512) void k_pvrow(const ushort* __restrict__ Vcm, const ushort* __restrict__ attn,
                                               ushort* __restrict__ out0) {
    __shared__ __align__(16) ushort Al[512 * 32];     // [c][v] 32KB
    __shared__ __align__(16) ushort Bl[96 * 32];      // [w][v] 6KB
    int h = blockIdx.x, bat = blockIdx.y;
    int tid = threadIdx.x, lane = tid & 63, wvid = tid >> 6;
    int wrm = wvid >> 1, wcn = wvid & 1;
    size_t vbase = (size_t)bat * C_ * P_ + (size_t)h * W_;
    size_t abase = ((size_t)bat * H_ + h) * W_ * L_;
    f32x4 acc[8][3] = {};
    for (int kb = 0; kb < 96; kb += 32) {
        #pragma unroll
        for (int i = 0; i < 4; ++i) {
            int u = tid + i * 512, row = u >> 2, seg = u & 3;
            int sg = (seg ^ FSW(row)) << 3;
            GLL16(&Vcm[vbase + (size_t)row * P_ + kb + sg], &Al[(size_t)u * 8]);
        }
        if (tid < 384) {
            int row = tid >> 2, seg = tid & 3;
            int sg = (seg ^ FSW(row)) << 3;
            GLL16(&attn[abase + (size_t)row * L_ + kb + sg], &Bl[(size_t)tid * 8]);
        }
        __syncthreads();
        int rr = lane & 15, gq = lane >> 4, ck = gq ^ FSW(rr);
        short8 fb[3];
        #pragma unroll
        for (int nt = 0; nt < 3; ++nt) fb[nt] = *(const short8*)&Bl[(wcn * 48 + nt * 16 + rr) * 32 + ck * 8];
        #pragma unroll
        for (int mt = 0; mt < 8; ++mt) {
            short8 fa = *(const short8*)&Al[(wrm * 128 + mt * 16 + rr) * 32 + ck * 8];
            #pragma unroll
            for (int nt = 0; nt < 3; ++nt)
                acc[mt][nt] = __builtin_amdgcn_mfma_f32_16x16x32_bf16(fa, fb[nt], acc[mt][nt], 0, 0, 0);
        }
        __syncthreads();
    }
    int rr = lane & 15, gq = lane >> 4;
    #pragma unroll
    for (int mt = 0; mt < 8; ++mt)
        #pragma unroll
        for (int nt = 0; nt < 3; ++nt) {
            int w = wcn * 48 + nt * 16 + rr;
            #pragma unroll
            for (int q = 0; q < 4; ++q) {
                int c = wrm * 128 + mt * 16 + gq * 4 + q;
                out0[((size_t)bat * C_ + c) * P_ + (size_t)h * W_ + w] = f2bf(acc[mt][nt][q]);
            }
        }
}

// ---------------- K9: per-(b,c) plane: out = x + gamma*(out0 + out1t^T), fully vectorized ----------------
__global__ __launch_bounds__(256) void k_final(const float* __restrict__ x, const ushort* __restrict__ out0,
                                               const ushort* __restrict__ out1t, const float* __restrict__ gamma,
                                               float* __restrict__ out) {
    __shared__ ushort t[96 * 100];                     // [h][w], pad 100
    int c = blockIdx.x, bat = blockIdx.y;
    const ushort* src = out1t + ((size_t)bat * C_ + c) * P_;   // plane [w][h]
    int tid = threadIdx.x;
    #pragma unroll
    for (int k = 0; k < 9; ++k) {                      // 96 w x 24 groups of 4 h
        int u = tid + k * 256, w = u / 24, h4 = (u % 24) * 4;
        us4 v = *(const us4*)&src[w * 96 + h4];
        t[(h4 + 0) * 100 + w] = v.x;
        t[(h4 + 1) * 100 + w] = v.y;
        t[(h4 + 2) * 100 + w] = v.z;
        t[(h4 + 3) * 100 + w] = v.w;
    }
    __syncthreads();
    float gm = gamma[0];
    size_t base = ((size_t)bat * C_ + c) * P_;
    #pragma unroll
    for (int k = 0; k < 9; ++k) {                      // 96 h x 24 groups of 4 w
        int u = tid + k * 256, h = u / 24, w4 = (u % 24) * 4;
        size_t idx = base + h * W_ + w4;
        float4 xv = *(const float4*)&x[idx];
        us4 o0 = *(const us4*)&out0[idx];
        us4 o1 = *(const us4*)&t[h * 100 + w4];
        float4 r;
        r.x = xv.x + gm * (bf2f(o0.x) + bf2f(o1.x));
        r.y = xv.y + gm * (bf2f(o0.y) + bf2f(o1.y));
        r.z = xv.z + gm * (bf2f(o0.z) + bf2f(o1.z));
        r.w = xv.w + gm * (bf2f(o0.w) + bf2f(o1.w));
        *(float4*)&out[idx] = r;
    }
}

extern "C" void kernel_launch(void* const* d_in, const int* in_sizes, int n_in,
                              void* d_out, int out_size, void* d_ws, size_t ws_size,
                              hipStream_t stream) {
    const float* x     = (const float*)d_in[0];
    const float* Wq    = (const float*)d_in[1];
    const float* bq    = (const float*)d_in[2];
    const float* Wk    = (const float*)d_in[3];
    const float* bk    = (const float*)d_in[4];
    const float* Wv    = (const float*)d_in[5];
    const float* bv    = (const float*)d_in[6];
    const float* gamma = (const float*)d_in[7];
    float* out = (float*)d_out;
    char* ws = (char*)d_ws;

    const size_t SZ  = (size_t)NP * C_ * 2;           // 75,497,472 B
    const size_t QKS = (size_t)NP * CQ_ * 2;          // 9,437,184 B
    // R0 [SZ]: xt (xt..proj) -> out1t (pvcol..final)
    ushort* xt     = (ushort*)(ws);
    ushort* out1t  = (ushort*)(ws);
    // R1 [SZ]: Vcm (proj..pvrow)
    ushort* Vcm    = (ushort*)(ws + SZ);
    // R2 [SZ]: Vt (vt..pvcol) -> out0 (pvrow..final)
    ushort* Vt     = (ushort*)(ws + 2 * SZ);
    ushort* out0   = Vt;
    // R3: Qb | Kb (proj..ecolsm) | attn (erow..pvrow) | Wall | ball
    ushort* Qb     = (ushort*)(ws + 3 * SZ);
    ushort* Kb     = (ushort*)(ws + 3 * SZ + QKS);
    ushort* attn   = (ushort*)(ws + 3 * SZ + 2 * QKS);
    size_t off_wall = 3 * SZ + 2 * QKS + (size_t)NP * L_ * 2;
    ushort* Wall   = (ushort*)(ws + off_wall);
    float*  ball   = (float*) (ws + off_wall + 640 * C_ * 2);

    k_wconv  <<<dim3(1280),       dim3(256),   0, stream>>>(Wq, Wk, Wv, bq, bk, bv, Wall, ball);
    k_xt     <<<dim3(144, 8, 8),  dim3(256),   0, stream>>>(x, xt);
    k_proj   <<<dim3(2880),       dim3(256),   0, stream>>>(xt, Wall, ball, Qb, Kb, Vcm);
    k_vt     <<<dim3(512, 8),     dim3(256),   0, stream>>>(Vcm, Vt);
    k_erow   <<<dim3(96, 8),      dim3(256),   0, stream>>>(Qb, Kb, attn);
    k_ecolsm <<<dim3(96, 8),      dim3(256),   0, stream>>>(Qb, Kb, attn);
    k_pvcol  <<<dim3(96, 8),      dim3(512),   0, stream>>>(Vt, attn, out1t);
    k_pvrow  <<<dim3(96, 8),      dim3(512),   0, stream>>>(Vcm, attn, out0);
    k_final  <<<dim3(512, 8),     dim3(256),   0, stream>>>(x, out0, out1t, gamma, out);
}

// Round 9
// 352.700 us; speedup vs baseline: 1.2918x; 1.0099x over previous
//
#include <hip/hip_runtime.h>
#include <stdint.h>

#define B_  8
#define C_  512
#define H_  96
#define W_  96
#define CQ_ 64
#define P_  (H_*W_)     // 9216 pixels per batch
#define NP  (B_*P_)     // 73728
#define L_  (W_+H_)     // 192 logits per pixel

typedef __attribute__((ext_vector_type(8))) short short8;
typedef __attribute__((ext_vector_type(4))) float f32x4;
typedef __attribute__((ext_vector_type(4))) unsigned short us4;

__device__ __forceinline__ ushort f2bf(float f) {
    uint32_t u = __builtin_bit_cast(uint32_t, f);
    u += 0x7fff + ((u >> 16) & 1);
    return (ushort)(u >> 16);
}
__device__ __forceinline__ float bf2f(ushort h) {
    uint32_t u = ((uint32_t)h) << 16;
    return __builtin_bit_cast(float, u);
}

// global -> LDS direct 16B copy (dest = wave-uniform base + lane*16)
#define GLL16(g, l) __builtin_amdgcn_global_load_lds( \
    (const __attribute__((address_space(1))) uint32_t*)(g), \
    (__attribute__((address_space(3))) uint32_t*)(l), 16, 0, 0)

// chunk swizzle for GEMM staging (proven r6): reads use ck = gq^FSW(rr)
#define FSW(r) (((r) >> 1) & 3)

// transpose-buffer group swizzle: element (r, c) of a 96x96 plane stored at
// t[r*128 + (((c>>2) ^ ((r>>2)&7))<<2) + (c&3)] -- us4-aligned, <=2-way banks both phases
__device__ __forceinline__ int TSW(int r, int c) {
    return r * 128 + ((((c >> 2) ^ ((r >> 2) & 7))) << 2) + (c & 3);
}

// ---------------- K0a: x (b,c,p) fp32 -> x_t (b,p,c) bf16 ----------------
__global__ __launch_bounds__(256) void k_xt(const float* __restrict__ x, ushort* __restrict__ xt) {
    __shared__ float tile[64 * 67];                    // pad 67: read bank-step 12 -> 2-way
    int p0 = blockIdx.x * 64, c0 = blockIdx.y * 64, bat = blockIdx.z;
    int tid = threadIdx.x;
    const float* xb = x + ((size_t)bat * C_ + c0) * P_ + p0;
    #pragma unroll
    for (int k = 0; k < 4; ++k) {                      // 64 c-rows x 16 float4
        int u = tid + k * 256, row = u >> 4, p4 = (u & 15) * 4;
        float4 v = *(const float4*)&xb[(size_t)row * P_ + p4];
        tile[row * 67 + p4]     = v.x;
        tile[row * 67 + p4 + 1] = v.y;
        tile[row * 67 + p4 + 2] = v.z;
        tile[row * 67 + p4 + 3] = v.w;
    }
    __syncthreads();
    ushort* o = xt + ((size_t)bat * P_ + p0) * C_ + c0;
    #pragma unroll
    for (int k = 0; k < 4; ++k) {                      // 64 p-rows x 16 us4 (c)
        int u = tid + k * 256, p = u >> 4, c4 = (u & 15) * 4;
        us4 v;
        v.x = f2bf(tile[(c4 + 0) * 67 + p]);
        v.y = f2bf(tile[(c4 + 1) * 67 + p]);
        v.z = f2bf(tile[(c4 + 2) * 67 + p]);
        v.w = f2bf(tile[(c4 + 3) * 67 + p]);
        *(us4*)&o[(size_t)p * C_ + c4] = v;
    }
}

// ---------------- K0b: weights -> bf16 combined [640][512]; ball[640] ----------------
__global__ __launch_bounds__(256) void k_wconv(const float* __restrict__ Wq, const float* __restrict__ Wk,
                                               const float* __restrict__ Wv, const float* __restrict__ bq,
                                               const float* __restrict__ bk, const float* __restrict__ bv,
                                               ushort* __restrict__ Wall, float* __restrict__ ball) {
    int idx = blockIdx.x * 256 + threadIdx.x;
    if (idx < 640) {
        float b;
        if (idx < 64)       b = bq[idx];
        else if (idx < 128) b = bk[idx - 64];
        else                b = bv[idx - 128];
        ball[idx] = b;
    }
    if (idx >= 640 * C_) return;
    int o = idx / C_, c = idx % C_;
    float v;
    if (o < 64)       v = Wq[o * C_ + c];
    else if (o < 128) v = Wk[(o - 64) * C_ + c];
    else              v = Wv[(o - 128) * C_ + c];
    Wall[idx] = f2bf(v);
}

// ---------------- K1: projection GEMM. M=640(o) x N=NP(pix), K=512, tile 128x128. ----------------
__global__ __launch_bounds__(256, 4) void k_proj(const ushort* __restrict__ xt, const ushort* __restrict__ Wall,
                                                 const float* __restrict__ ball,
                                                 ushort* __restrict__ Qb, ushort* __restrict__ Kb,
                                                 ushort* __restrict__ Vcm) {
    __shared__ __align__(16) ushort Al[128 * 32];     // [o][k] 8KB linear
    __shared__ __align__(16) ushort Bl[128 * 32];     // [pix][k] 8KB linear
    __shared__ __align__(16) ushort Tl[128 * 68];     // 17KB transpose buffer (m0==0 epilogue)
    int tid = threadIdx.x, lane = tid & 63, wv = tid >> 6;
    int wr = wv >> 1, wc = wv & 1;
    int wg = ((int)blockIdx.x & 7) * 360 + ((int)blockIdx.x >> 3);
    int m0 = (wg % 5) * 128;
    int n0 = (wg / 5) * 128;
    f32x4 acc[4][4] = {};
    for (int kb = 0; kb < C_; kb += 32) {
        #pragma unroll
        for (int i = 0; i < 2; ++i) {
            int u = tid + i * 256, row = u >> 2, seg = u & 3;
            int sg = (seg ^ FSW(row)) << 3;
            GLL16(&Wall[(size_t)(m0 + row) * C_ + kb + sg], &Al[(size_t)u * 8]);
            GLL16(&xt[(size_t)(n0 + row) * C_ + kb + sg],   &Bl[(size_t)u * 8]);
        }
        __syncthreads();
        int rr = lane & 15, gq = lane >> 4, ck = gq ^ FSW(rr);
        short8 fb[4];
        #pragma unroll
        for (int nt = 0; nt < 4; ++nt) fb[nt] = *(const short8*)&Bl[(wc * 64 + nt * 16 + rr) * 32 + ck * 8];
        #pragma unroll
        for (int mt = 0; mt < 4; ++mt) {
            short8 fa = *(const short8*)&Al[(wr * 64 + mt * 16 + rr) * 32 + ck * 8];
            #pragma unroll
            for (int nt = 0; nt < 4; ++nt)
                acc[mt][nt] = __builtin_amdgcn_mfma_f32_16x16x32_bf16(fa, fb[nt], acc[mt][nt], 0, 0, 0);
        }
        __syncthreads();
    }
    int rr = lane & 15, gq = lane >> 4;
    int bat = n0 / P_, pb0 = n0 - bat * P_;
    if (m0 == 0) {
        #pragma unroll
        for (int pass = 0; pass < 2; ++pass) {
            __syncthreads();
            if (wr == pass) {
                #pragma unroll
                for (int mt = 0; mt < 4; ++mt)
                    #pragma unroll
                    for (int nt = 0; nt < 4; ++nt) {
                        int col = wc * 64 + nt * 16 + rr;
                        #pragma unroll
                        for (int q = 0; q < 4; ++q) {
                            int ol = mt * 16 + gq * 4 + q;           // 0..63
                            Tl[col * 68 + ol] = f2bf(acc[mt][nt][q] + ball[pass * 64 + ol]);
                        }
                    }
            }
            __syncthreads();
            ushort* dst = pass ? Kb : Qb;
            int p = tid >> 1, off = (tid & 1) * 32;
            #pragma unroll
            for (int j = 0; j < 8; ++j)
                *(us4*)&dst[(size_t)(n0 + p) * CQ_ + off + j * 4] = *(const us4*)&Tl[p * 68 + off + j * 4];
        }
    } else {
        #pragma unroll
        for (int mt = 0; mt < 4; ++mt)
            #pragma unroll
            for (int nt = 0; nt < 4; ++nt) {
                int col = wc * 64 + nt * 16 + rr;
                #pragma unroll
                for (int q = 0; q < 4; ++q) {
                    int o = m0 + wr * 64 + mt * 16 + gq * 4 + q;     // 128..639
                    int c = o - 128;
                    Vcm[((size_t)bat * C_ + c) * P_ + pb0 + col] = f2bf(acc[mt][nt][q] + ball[o]);
                }
            }
    }
}

// ---------------- K3: Vcm (b,c,h,w) -> Vt (b,w,c,h); one plane per block, swizzled LDS ----------------
__global__ __launch_bounds__(256) void k_vt(const ushort* __restrict__ Vcm, ushort* __restrict__ Vt) {
    __shared__ ushort t[96 * 128];                     // group-XOR swizzled plane
    int c = blockIdx.x, bat = blockIdx.y;
    const ushort* src = Vcm + ((size_t)(bat * C_ + c)) * P_;
    int tid = threadIdx.x;
    #pragma unroll
    for (int k = 0; k < 9; ++k) {                      // 96 h x 24 us4 of w
        int u = tid + k * 256, h = u / 24, w4 = (u % 24) * 4;
        us4 v = *(const us4*)&src[h * 96 + w4];
        t[TSW(h, w4)]     = v.x;
        t[TSW(h, w4) + 1] = v.y;                       // same group, slots 0..3
        t[TSW(h, w4) + 2] = v.z;
        t[TSW(h, w4) + 3] = v.w;
    }
    __syncthreads();
    #pragma unroll
    for (int k = 0; k < 9; ++k) {                      // 96 w x 24 us4 of h
        int u = tid + k * 256, w = u / 24, h4 = (u % 24) * 4;
        us4 o;
        o.x = t[TSW(h4 + 0, w)];
        o.y = t[TSW(h4 + 1, w)];
        o.z = t[TSW(h4 + 2, w)];
        o.w = t[TSW(h4 + 3, w)];
        *(us4*)&Vt[((size_t)(bat * W_ + w) * C_ + c) * H_ + h4] = o;
    }
}

// ---------------- K4: e_row. block (h,b): M=96(w) N=96(v) K=64; bf16 into attn[pix][0:96] ----------------
#define LSTR 40
__global__ __launch_bounds__(256) void k_erow(const ushort* __restrict__ Qb, const ushort* __restrict__ Kb,
                                              ushort* __restrict__ attn) {
    __shared__ __align__(16) ushort Al[96 * LSTR];
    __shared__ __align__(16) ushort Bl[96 * LSTR];
    int h = blockIdx.x, bat = blockIdx.y;
    int tid = threadIdx.x, lane = tid & 63, wvid = tid >> 6;
    int wr = wvid >> 1, wc = wvid & 1;                 // wave tile 48x48
    size_t base = ((size_t)bat * H_ + h) * W_;
    f32x4 acc[3][3] = {};
    for (int kb = 0; kb < CQ_; kb += 32) {
        for (int s = tid; s < 96 * 4; s += 256) {
            int row = s >> 2, seg = s & 3;
            *(short8*)&Al[row * LSTR + seg * 8] = *(const short8*)&Qb[(base + row) * CQ_ + kb + seg * 8];
            *(short8*)&Bl[row * LSTR + seg * 8] = *(const short8*)&Kb[(base + row) * CQ_ + kb + seg * 8];
        }
        __syncthreads();
        int rr = lane & 15, gq = lane >> 4;
        #pragma unroll
        for (int mt = 0; mt < 3; ++mt) {
            short8 fa = *(const short8*)&Al[(wr * 48 + mt * 16 + rr) * LSTR + gq * 8];
            #pragma unroll
            for (int nt = 0; nt < 3; ++nt) {
                short8 fb = *(const short8*)&Bl[(wc * 48 + nt * 16 + rr) * LSTR + gq * 8];
                acc[mt][nt] = __builtin_amdgcn_mfma_f32_16x16x32_bf16(fa, fb, acc[mt][nt], 0, 0, 0);
            }
        }
        __syncthreads();
    }
    int rr = lane & 15, gq = lane >> 4;
    #pragma unroll
    for (int mt = 0; mt < 3; ++mt)
        #pragma unroll
        for (int nt = 0; nt < 3; ++nt)
            #pragma unroll
            for (int q = 0; q < 4; ++q) {
                int w = wr * 48 + mt * 16 + gq * 4 + q;
                int v = wc * 48 + nt * 16 + rr;
                attn[(base + w) * L_ + v] = f2bf(acc[mt][nt][q]);
            }
}

// ---------------- K5: e_col GEMM + fused softmax (in-place on attn). block (w,b). ----------------
__global__ __launch_bounds__(256) void k_ecolsm(const ushort* __restrict__ Qb, const ushort* __restrict__ Kb,
                                                ushort* __restrict__ attn) {
    __shared__ __align__(16) ushort Al[96 * LSTR];
    __shared__ __align__(16) ushort Bl[96 * LSTR];
    __shared__ ushort ecl[96 * 100];                   // [h][g] bf16, padded
    int w = blockIdx.x, bat = blockIdx.y;
    int tid = threadIdx.x, lane = tid & 63, wvid = tid >> 6;
    int wr = wvid >> 1, wc = wvid & 1;
    f32x4 acc[3][3] = {};
    for (int kb = 0; kb < CQ_; kb += 32) {
        for (int s = tid; s < 96 * 4; s += 256) {
            int row = s >> 2, seg = s & 3;
            size_t px = ((size_t)bat * H_ + row) * W_ + w;
            *(short8*)&Al[row * LSTR + seg * 8] = *(const short8*)&Qb[px * CQ_ + kb + seg * 8];
            *(short8*)&Bl[row * LSTR + seg * 8] = *(const short8*)&Kb[px * CQ_ + kb + seg * 8];
        }
        __syncthreads();
        int rr = lane & 15, gq = lane >> 4;
        #pragma unroll
        for (int mt = 0; mt < 3; ++mt) {
            short8 fa = *(const short8*)&Al[(wr * 48 + mt * 16 + rr) * LSTR + gq * 8];
            #pragma unroll
            for (int nt = 0; nt < 3; ++nt) {
                short8 fb = *(const short8*)&Bl[(wc * 48 + nt * 16 + rr) * LSTR + gq * 8];
                acc[mt][nt] = __builtin_amdgcn_mfma_f32_16x16x32_bf16(fa, fb, acc[mt][nt], 0, 0, 0);
            }
        }
        __syncthreads();
    }
    {
        int rr = lane & 15, gq = lane >> 4;
        #pragma unroll
        for (int mt = 0; mt < 3; ++mt)
            #pragma unroll
            for (int nt = 0; nt < 3; ++nt)
                #pragma unroll
                for (int q = 0; q < 4; ++q) {
                    int hh = wr * 48 + mt * 16 + gq * 4 + q;
                    int gg = wc * 48 + nt * 16 + rr;
                    ecl[hh * 100 + gg] = f2bf(acc[mt][nt][q]);
                }
    }
    __syncthreads();
    for (int h = wvid; h < H_; h += 4) {
        size_t pix = ((size_t)bat * H_ + h) * W_ + w;
        ushort* ap = attn + pix * L_;
        float a  = bf2f(ap[lane]);
        float b  = (lane < 32) ? bf2f(ap[64 + lane]) : -1e30f;
        float c0 = bf2f(ecl[h * 100 + lane]);
        float c1 = (lane < 32) ? bf2f(ecl[h * 100 + 64 + lane]) : -1e30f;
        float m = fmaxf(fmaxf(a, b), fmaxf(c0, c1));
        #pragma unroll
        for (int off = 32; off; off >>= 1) m = fmaxf(m, __shfl_xor(m, off));
        float ea = __expf(a - m), eb = (lane < 32) ? __expf(b - m) : 0.0f;
        float ec0 = __expf(c0 - m), ec1 = (lane < 32) ? __expf(c1 - m) : 0.0f;
        float s = ea + eb + ec0 + ec1;
        #pragma unroll
        for (int off = 32; off; off >>= 1) s += __shfl_xor(s, off);
        float inv = 1.0f / s;
        ap[lane] = f2bf(ea * inv);
        ap[96 + lane] = f2bf(ec0 * inv);
        if (lane < 32) {
            ap[64 + lane] = f2bf(eb * inv);
            ap[160 + lane] = f2bf(ec1 * inv);
        }
    }
}

// ---------------- K8: col PV. block (w,b): M=512(c) N=96(h) K=96(g); out (b,c,w,h) ----------------
__global__ __launch_bounds__(512) void k_pvcol(const ushort* __restrict__ Vt, const ushort* __restrict__ attn,
                                               ushort* __restrict__ out1t) {
    __shared__ __align__(16) ushort Al[512 * 32];     // [c][g] 32KB linear
    __shared__ __align__(16) ushort Bl[96 * 32];      // [h][g] 6KB linear
    int w = blockIdx.x, bat = blockIdx.y;
    int tid = threadIdx.x, lane = tid & 63, wvid = tid >> 6;
    int wrm = wvid >> 1, wcn = wvid & 1;              // 4m x 2n, wave tile 128x48
    size_t vbase = ((size_t)bat * W_ + w) * C_ * H_;
    size_t abase = ((size_t)bat * P_ + w) * L_ + W_;
    f32x4 acc[8][3] = {};
    for (int kb = 0; kb < 96; kb += 32) {
        #pragma unroll
        for (int i = 0; i < 4; ++i) {
            int u = tid + i * 512, row = u >> 2, seg = u & 3;
            int sg = (seg ^ FSW(row)) << 3;
            GLL16(&Vt[vbase + (size_t)row * H_ + kb + sg], &Al[(size_t)u * 8]);
        }
        if (tid < 384) {
            int row = tid >> 2, seg = tid & 3;
            int sg = (seg ^ FSW(row)) << 3;
            GLL16(&attn[abase + (size_t)row * (W_ * L_) + kb + sg], &Bl[(size_t)tid * 8]);
        }
        __syncthreads();
        int rr = lane & 15, gq = lane >> 4, ck = gq ^ FSW(rr);
        short8 fb[3];
        #pragma unroll
        for (int nt = 0; nt < 3; ++nt) fb[nt] = *(const short8*)&Bl[(wcn * 48 + nt * 16 + rr) * 32 + ck * 8];
        #pragma unroll
        for (int mt = 0; mt < 8; ++mt) {
            short8 fa = *(const short8*)&Al[(wrm * 128 + mt * 16 + rr) * 32 + ck * 8];
            #pragma unroll
            for (int nt = 0; nt < 3; ++nt)
                acc[mt][nt] = __builtin_amdgcn_mfma_f32_16x16x32_bf16(fa, fb[nt], acc[mt][nt], 0, 0, 0);
        }
        __syncthreads();
    }
    int rr = lane & 15, gq = lane >> 4;
    #pragma unroll
    for (int mt = 0; mt < 8; ++mt)
        #pragma unroll
        for (int nt = 0; nt < 3; ++nt) {
            int hh = wcn * 48 + nt * 16 + rr;
            #pragma unroll
            for (int q = 0; q < 4; ++q) {
                int c = wrm * 128 + mt * 16 + gq * 4 + q;
                out1t[((size_t)(bat * C_ + c) * W_ + w) * H_ + hh] = f2bf(acc[mt][nt][q]);
            }
        }
}

// ---------------- K7: row PV. block (h,b): M=512(c) N=96(w) K=96(v) ----------------
__global__ __launch_bounds__(512) void k_pvrow(const ushort* __restrict__ Vcm, const ushort* __restrict__ attn,
                                               ushort* __restrict__ out0) {
    __shared__ __align__(16) ushort Al[512 * 32];     // [c][v] 32KB
    __shared__ __align__(16) ushort Bl[96 * 32];      // [w][v] 6KB
    int h = blockIdx.x, bat = blockIdx.y;
    int tid = threadIdx.x, lane = tid & 63, wvid = tid >> 6;
    int wrm = wvid >> 1, wcn = wvid & 1;
    size_t vbase = (size_t)bat * C_ * P_ + (size_t)h * W_;
    size_t abase = ((size_t)bat * H_ + h) * W_ * L_;
    f32x4 acc[8][3] = {};
    for (int kb = 0; kb < 96; kb += 32) {
        #pragma unroll
        for (int i = 0; i < 4; ++i) {
            int u = tid + i * 512, row = u >> 2, seg = u & 3;
            int sg = (seg ^ FSW(row)) << 3;
            GLL16(&Vcm[vbase + (size_t)row * P_ + kb + sg], &Al[(size_t)u * 8]);
        }
        if (tid < 384) {
            int row = tid >> 2, seg = tid & 3;
            int sg = (seg ^ FSW(row)) << 3;
            GLL16(&attn[abase + (size_t)row * L_ + kb + sg], &Bl[(size_t)tid * 8]);
        }
        __syncthreads();
        int rr = lane & 15, gq = lane >> 4, ck = gq ^ FSW(rr);
        short8 fb[3];
        #pragma unroll
        for (int nt = 0; nt < 3; ++nt) fb[nt] = *(const short8*)&Bl[(wcn * 48 + nt * 16 + rr) * 32 + ck * 8];
        #pragma unroll
        for (int mt = 0; mt < 8; ++mt) {
            short8 fa = *(const short8*)&Al[(wrm * 128 + mt * 16 + rr) * 32 + ck * 8];
            #pragma unroll
            for (int nt = 0; nt < 3; ++nt)
                acc[mt][nt] = __builtin_amdgcn_mfma_f32_16x16x32_bf16(fa, fb[nt], acc[mt][nt], 0, 0, 0);
        }
        __syncthreads();
    }
    int rr = lane & 15, gq = lane >> 4;
    #pragma unroll
    for (int mt = 0; mt < 8; ++mt)
        #pragma unroll
        for (int nt = 0; nt < 3; ++nt) {
            int w = wcn * 48 + nt * 16 + rr;
            #pragma unroll
            for (int q = 0; q < 4; ++q) {
                int c = wrm * 128 + mt * 16 + gq * 4 + q;
                out0[((size_t)bat * C_ + c) * P_ + (size_t)h * W_ + w] = f2bf(acc[mt][nt][q]);
            }
        }
}

// ---------------- K9: out = x + gamma*(out0 + out1t^T), swizzled transpose LDS ----------------
__global__ __launch_bounds__(256) void k_final(const float* __restrict__ x, const ushort* __restrict__ out0,
                                               const ushort* __restrict__ out1t, const float* __restrict__ gamma,
                                               float* __restrict__ out) {
    __shared__ ushort t[96 * 128];                     // group-XOR swizzled [h][w] plane
    int c = blockIdx.x, bat = blockIdx.y;
    const ushort* src = out1t + ((size_t)bat * C_ + c) * P_;   // plane [w][h]
    int tid = threadIdx.x;
    #pragma unroll
    for (int k = 0; k < 9; ++k) {                      // 96 w x 24 us4 of h
        int u = tid + k * 256, w = u / 24, h4 = (u % 24) * 4;
        us4 v = *(const us4*)&src[w * 96 + h4];
        t[TSW(h4 + 0, w)] = v.x;
        t[TSW(h4 + 1, w)] = v.y;
        t[TSW(h4 + 2, w)] = v.z;
        t[TSW(h4 + 3, w)] = v.w;
    }
    __syncthreads();
    float gm = gamma[0];
    size_t base = ((size_t)bat * C_ + c) * P_;
    #pragma unroll
    for (int k = 0; k < 9; ++k) {                      // 96 h x 24 us4 of w
        int u = tid + k * 256, h = u / 24, w4 = (u % 24) * 4;
        size_t idx = base + h * W_ + w4;
        float4 xv = *(const float4*)&x[idx];
        us4 o0 = *(const us4*)&out0[idx];
        us4 o1 = *(const us4*)&t[TSW(h, w4)];
        float4 r;
        r.x = xv.x + gm * (bf2f(o0.x) + bf2f(o1.x));
        r.y = xv.y + gm * (bf2f(o0.y) + bf2f(o1.y));
        r.z = xv.z + gm * (bf2f(o0.z) + bf2f(o1.z));
        r.w = xv.w + gm * (bf2f(o0.w) + bf2f(o1.w));
        *(float4*)&out[idx] = r;
    }
}

extern "C" void kernel_launch(void* const* d_in, const int* in_sizes, int n_in,
                              void* d_out, int out_size, void* d_ws, size_t ws_size,
                              hipStream_t stream) {
    const float* x     = (const float*)d_in[0];
    const float* Wq    = (const float*)d_in[1];
    const float* bq    = (const float*)d_in[2];
    const float* Wk    = (const float*)d_in[3];
    const float* bk    = (const float*)d_in[4];
    const float* Wv    = (const float*)d_in[5];
    const float* bv    = (const float*)d_in[6];
    const float* gamma = (const float*)d_in[7];
    float* out = (float*)d_out;
    char* ws = (char*)d_ws;

    const size_t SZ  = (size_t)NP * C_ * 2;           // 75,497,472 B
    const size_t QKS = (size_t)NP * CQ_ * 2;          // 9,437,184 B
    ushort* xt     = (ushort*)(ws);
    ushort* out1t  = (ushort*)(ws);
    ushort* Vcm    = (ushort*)(ws + SZ);
    ushort* Vt     = (ushort*)(ws + 2 * SZ);
    ushort* out0   = Vt;
    ushort* Qb     = (ushort*)(ws + 3 * SZ);
    ushort* Kb     = (ushort*)(ws + 3 * SZ + QKS);
    ushort* attn   = (ushort*)(ws + 3 * SZ + 2 * QKS);
    size_t off_wall = 3 * SZ + 2 * QKS + (size_t)NP * L_ * 2;
    ushort* Wall   = (ushort*)(ws + off_wall);
    float*  ball   = (float*) (ws + off_wall + 640 * C_ * 2);

    k_wconv  <<<dim3(1280),       dim3(256),   0, stream>>>(Wq, Wk, Wv, bq, bk, bv, Wall, ball);
    k_xt     <<<dim3(144, 8, 8),  dim3(256),   0, stream>>>(x, xt);
    k_proj   <<<dim3(2880),       dim3(256),   0, stream>>>(xt, Wall, ball, Qb, Kb, Vcm);
    k_vt     <<<dim3(512, 8),     dim3(256),   0, stream>>>(Vcm, Vt);
    k_erow   <<<dim3(96, 8),      dim3(256),   0, stream>>>(Qb, Kb, attn);
    k_ecolsm <<<dim3(96, 8),      dim3(256),   0, stream>>>(Qb, Kb, attn);
    k_pvcol  <<<dim3(96, 8),      dim3(512),   0, stream>>>(Vt, attn, out1t);
    k_pvrow  <<<dim3(96, 8),      dim3(512),   0, stream>>>(Vcm, attn, out0);
    k_final  <<<dim3(512, 8),     dim3(256),   0, stream>>>(x, out0, out1t, gamma, out);
}